// Round 12
// baseline (379.269 us; speedup 1.0000x reference)
//
#include <hip/hip_runtime.h>
#include <stdint.h>

// out[e] = edge_attr[e] / segsum(edge_attr, row)[col[e]]
//
// Counting-sort by 8192-wide node bucket, exact atomic-free scatter offsets.
// Round-12: reduce + gather rebuilt on __builtin_amdgcn_global_load_lds
// (async global->LDS, no VGPR round-trip). Two rounds proved the compiler
// won't allocate registers for load staging (VGPR 8/20/36) -> per-thread MLP
// stuck at 1-2 lines. The async path queues unlimited loads with vmcnt
// counting: reduce = per-wave double-buffered contiguous staging (vmcnt(2),
// never 0 in steady state); gather = 32 random 4B table gathers in flight
// per thread batch (per-lane global addr, wave-uniform LDS dest).
//   P1 hist / P2 totals / P3 bases / P4 offsets / P5 scatter (round-10 form)
//   P6 reduce (async stage) / P7 recip (f32 table) / P8 gather (async gather)
// Fallback (small ws): direct-atomic version.

typedef int      v4i __attribute__((ext_vector_type(4)));
typedef float    v4f __attribute__((ext_vector_type(4)));
typedef unsigned v4u __attribute__((ext_vector_type(4)));
using ull = unsigned long long;

#define BKT_BITS 13
#define BKT_W    (1 << BKT_BITS)      // 8192 nodes per bucket
#define NB       128                   // supports N <= 1,048,576
#define NMAX     (NB << BKT_BITS)
#define TILE     4096
#define BLOCK1   512
#define BLOCK2   512

#define GLD_LDS(G, L, SZ) __builtin_amdgcn_global_load_lds((G), (L), (SZ), 0, 0)

// ---------------- fast path ----------------

__global__ __launch_bounds__(BLOCK1) void hist_kernel(
    const int* __restrict__ row, int* __restrict__ histG, int E)
{
    __shared__ int h[NB];
    const int t = threadIdx.x;
    const long base = (long)blockIdx.x * TILE;
    if (t < NB) h[t] = 0;
    __syncthreads();
    if (base + TILE <= (long)E) {
        #pragma unroll
        for (int k = 0; k < 2; ++k) {
            const long e0 = base + ((long)(k * BLOCK1 + t) << 2);
            const v4i rv = *reinterpret_cast<const v4i*>(row + e0);  // regular: row -> L3 for scatter
            atomicAdd(&h[rv.x >> BKT_BITS], 1);
            atomicAdd(&h[rv.y >> BKT_BITS], 1);
            atomicAdd(&h[rv.z >> BKT_BITS], 1);
            atomicAdd(&h[rv.w >> BKT_BITS], 1);
        }
    } else {
        for (int k = 0; k < 2; ++k) {
            const long e0 = base + ((long)(k * BLOCK1 + t) << 2);
            for (int j = 0; j < 4; ++j)
                if (e0 + j < (long)E) atomicAdd(&h[row[e0 + j] >> BKT_BITS], 1);
        }
    }
    __syncthreads();
    if (t < NB) histG[(size_t)blockIdx.x * NB + t] = h[t];
}

__global__ __launch_bounds__(256) void totals_kernel(
    const int* __restrict__ histG, int* __restrict__ totals, int nTiles)
{
    __shared__ int s[256];
    const int b = blockIdx.x;
    int acc = 0;
    for (int t = threadIdx.x; t < nTiles; t += 256)
        acc += histG[(size_t)t * NB + b];
    s[threadIdx.x] = acc;
    __syncthreads();
    for (int o = 128; o > 0; o >>= 1) {
        if (threadIdx.x < o) s[threadIdx.x] += s[threadIdx.x + o];
        __syncthreads();
    }
    if (threadIdx.x == 0) totals[b] = s[0];
}

__global__ __launch_bounds__(NB) void bases_kernel(
    const int* __restrict__ totals, int* __restrict__ bases)
{
    __shared__ int s[NB];
    const int t = threadIdx.x;
    const int rc = (totals[t] + 1) & ~1;      // even-rounded -> 16B-aligned regions
    s[t] = rc;
    __syncthreads();
    for (int off = 1; off < NB; off <<= 1) {
        const int v = (t >= off) ? s[t - off] : 0;
        __syncthreads();
        s[t] += v;
        __syncthreads();
    }
    bases[t] = s[t] - rc;
}

__global__ __launch_bounds__(256) void offsets_kernel(
    const int* __restrict__ histG, const int* __restrict__ bases,
    int* __restrict__ offG, int nTiles)
{
    __shared__ int s[256];
    const int b = blockIdx.x;
    const int seg = (nTiles + 255) >> 8;
    const int t0 = threadIdx.x * seg;
    int acc = 0;
    for (int k = 0; k < seg; ++k) {
        const int t = t0 + k;
        if (t < nTiles) acc += histG[(size_t)t * NB + b];
    }
    s[threadIdx.x] = acc;
    __syncthreads();
    for (int off = 1; off < 256; off <<= 1) {
        const int v = (threadIdx.x >= off) ? s[threadIdx.x - off] : 0;
        __syncthreads();
        s[threadIdx.x] += v;
        __syncthreads();
    }
    int run = bases[b] + s[threadIdx.x] - acc;     // exclusive base for my segment
    for (int k = 0; k < seg; ++k) {
        const int t = t0 + k;
        if (t < nTiles) {
            offG[(size_t)t * NB + b] = run;
            run += histG[(size_t)t * NB + b];
        }
    }
}

__global__ __launch_bounds__(BLOCK1) void scatter_kernel(
    const int* __restrict__ row, const float* __restrict__ attr,
    const int* __restrict__ offG, ull* __restrict__ pairsG, int E)
{
    __shared__ int cnt[NB];
    __shared__ int scanb[NB];
    __shared__ int gbase[NB];
    __shared__ ull pairs[TILE];                    // 32 KB

    const int  t    = threadIdx.x;
    const long base = (long)blockIdx.x * TILE;
    const bool full = (base + TILE <= (long)E);

    if (t < NB) cnt[t] = 0;
    __syncthreads();

    int r[8]; float a[8]; int rk[8];
    if (full) {
        #pragma unroll
        for (int k = 0; k < 2; ++k) {
            const long e0 = base + ((long)(k * BLOCK1 + t) << 2);
            const v4i rv = *reinterpret_cast<const v4i*>(row + e0);   // L3-hot from hist
            const v4f av = __builtin_nontemporal_load(reinterpret_cast<const v4f*>(attr + e0));
            r[k*4+0]=rv.x; r[k*4+1]=rv.y; r[k*4+2]=rv.z; r[k*4+3]=rv.w;
            a[k*4+0]=av.x; a[k*4+1]=av.y; a[k*4+2]=av.z; a[k*4+3]=av.w;
        }
        #pragma unroll
        for (int i = 0; i < 8; ++i)
            rk[i] = atomicAdd(&cnt[r[i] >> BKT_BITS], 1);
    } else {
        for (int k = 0; k < 2; ++k) {
            const long e0 = base + ((long)(k * BLOCK1 + t) << 2);
            for (int j = 0; j < 4; ++j) {
                const int i = k*4 + j;
                if (e0 + j < (long)E) {
                    r[i] = row[e0 + j]; a[i] = attr[e0 + j];
                    rk[i] = atomicAdd(&cnt[r[i] >> BKT_BITS], 1);
                } else r[i] = -1;
            }
        }
    }
    __syncthreads();

    // wave-0 exclusive scan of the 128 bucket counts (2 bins/lane)
    if (t < 64) {
        const int h0 = cnt[2*t], h1 = cnt[2*t+1];
        const int sum = h0 + h1;
        int x = sum;
        #pragma unroll
        for (int off = 1; off < 64; off <<= 1) {
            const int y = __shfl_up(x, off);
            if (t >= off) x += y;
        }
        const int excl = x - sum;
        scanb[2*t]   = excl;
        scanb[2*t+1] = excl + h0;
    }
    if (t < NB) gbase[t] = offG[(size_t)blockIdx.x * NB + t];   // exact, no atomic
    __syncthreads();

    #pragma unroll
    for (int i = 0; i < 8; ++i)
        if (r[i] >= 0)
            pairs[scanb[r[i] >> BKT_BITS] + rk[i]] =
                ((ull)__float_as_uint(a[i]) << 32) | (unsigned)r[i];
    __syncthreads();

    const int total = full ? TILE : (int)((long)E - base);
    for (int s = t; s < total; s += BLOCK1) {
        const ull p  = pairs[s];
        const int bb = (int)(((unsigned)p) >> BKT_BITS);
        const size_t dst = (size_t)gbase[bb] + (size_t)(s - scanb[bb]);
        pairsG[dst] = p;                           // REGULAR store -> L3 keeps it for reduce
    }
}

// reduce: per-wave async double-buffered staging via global_load_lds
__global__ __launch_bounds__(BLOCK2) void reduce_kernel(
    const ull* __restrict__ pairsG, const int* __restrict__ totals,
    const int* __restrict__ bases, float* __restrict__ partial, int nSplit)
{
    __shared__ float bins[BKT_W];         // 32 KB
    __shared__ ull   stage[2][2048];      // 32 KB (2 bufs x 2048 pairs)
    const int b = blockIdx.x / nSplit;
    const int q = blockIdx.x % nSplit;
    const int t = threadIdx.x;
    const int w = t >> 6, l = t & 63;

    for (int i = t; i < BKT_W; i += BLOCK2) bins[i] = 0.0f;
    __syncthreads();

    const int cnt = totals[b];
    const ull* src = pairsG + (size_t)bases[b];    // even base -> 16B aligned
    const int nChunks = cnt >> 11;                  // 2048-pair chunks

    // wave w owns pairs [w*256, w*256+256) of each chunk: 2 x 16B gld_lds
    int k = q;
    int cur = 0;
    if (k < nChunks) {
        const ull* gp = src + ((size_t)k << 11) + (w << 8);
        GLD_LDS(gp + l*2,       &stage[cur][(w << 8)],       16);
        GLD_LDS(gp + 128 + l*2, &stage[cur][(w << 8) + 128], 16);
    }
    while (k < nChunks) {
        const int kn = k + nSplit;
        if (kn < nChunks) {
            const ull* gp = src + ((size_t)kn << 11) + (w << 8);
            GLD_LDS(gp + l*2,       &stage[cur ^ 1][(w << 8)],       16);
            GLD_LDS(gp + 128 + l*2, &stage[cur ^ 1][(w << 8) + 128], 16);
            asm volatile("s_waitcnt vmcnt(2)" ::: "memory");   // oldest 2 done, next 2 in flight
        } else {
            asm volatile("s_waitcnt vmcnt(0)" ::: "memory");
        }
        __builtin_amdgcn_sched_barrier(0);
        const v4u* sp = reinterpret_cast<const v4u*>(&stage[cur][(w << 8) + l*4]);
        const v4u x0 = sp[0];
        const v4u x1 = sp[1];
        atomicAdd(&bins[x0.x & (BKT_W-1)], __uint_as_float(x0.y));
        atomicAdd(&bins[x0.z & (BKT_W-1)], __uint_as_float(x0.w));
        atomicAdd(&bins[x1.x & (BKT_W-1)], __uint_as_float(x1.y));
        atomicAdd(&bins[x1.z & (BKT_W-1)], __uint_as_float(x1.w));
        cur ^= 1;
        k = kn;
    }

    if (q == 0) {                                   // tail (cnt % 2048)
        for (int o = (nChunks << 11) + t; o < cnt; o += BLOCK2) {
            const ull p = src[o];
            atomicAdd(&bins[(unsigned)p & (BKT_W-1)], __uint_as_float((unsigned)(p >> 32)));
        }
    }
    __syncthreads();

    float* dst = partial + (size_t)q * NMAX + ((size_t)b << BKT_BITS);
    for (int i = t; i < BKT_W; i += BLOCK2)
        dst[i] = bins[i];
}

__global__ void recip_kernel(const float* __restrict__ partial,
                             float* __restrict__ rnF,
                             const int* __restrict__ Np, int nSplit) {
    const int N = *Np;
    const int stride = gridDim.x * blockDim.x;
    for (int i = blockIdx.x * blockDim.x + threadIdx.x; i < N; i += stride) {
        float s = 0.0f;
        for (int q = 0; q < nSplit; ++q) s += partial[(size_t)q * NMAX + i];
        rnF[i] = 1.0f / s;
    }
}

// gather: async random table gathers into LDS (per-lane global addr)
__global__ __launch_bounds__(256, 4) void gather_gld_kernel(
    const int* __restrict__ col, const float* __restrict__ attr,
    const float* __restrict__ rnF, float* __restrict__ out, int E)
{
    __shared__ float gstage[4][32][64];   // 32 KB, partitioned per wave
    const int t = threadIdx.x, w = t >> 6, l = t & 63;
    const int E4 = E >> 2;
    const v4i* col4  = reinterpret_cast<const v4i*>(col);
    const v4f* attr4 = reinterpret_cast<const v4f*>(attr);
    v4f*       out4  = reinterpret_cast<v4f*>(out);
    const int groups = (E4 + 2047) >> 11;          // 2048 quads per group

    for (int g = blockIdx.x; g < groups; g += gridDim.x) {
        const int q0 = (g << 11) + t;
        v4i c[8]; v4f a[8];
        #pragma unroll
        for (int j = 0; j < 8; ++j) {
            const int qi = q0 + (j << 8);
            const int s = qi < E4 ? qi : 0;
            c[j] = __builtin_nontemporal_load(col4 + s);
            a[j] = __builtin_nontemporal_load(attr4 + s);
        }
        #pragma unroll
        for (int j = 0; j < 8; ++j) {              // 32 async gathers in flight
            GLD_LDS(rnF + c[j].x, &gstage[w][j*4+0][0], 4);
            GLD_LDS(rnF + c[j].y, &gstage[w][j*4+1][0], 4);
            GLD_LDS(rnF + c[j].z, &gstage[w][j*4+2][0], 4);
            GLD_LDS(rnF + c[j].w, &gstage[w][j*4+3][0], 4);
        }
        asm volatile("s_waitcnt vmcnt(0)" ::: "memory");
        __builtin_amdgcn_sched_barrier(0);
        #pragma unroll
        for (int j = 0; j < 8; ++j) {
            const int qi = q0 + (j << 8);
            if (qi < E4) {
                v4f o;
                o.x = gstage[w][j*4+0][l] * a[j].x;
                o.y = gstage[w][j*4+1][l] * a[j].y;
                o.z = gstage[w][j*4+2][l] * a[j].z;
                o.w = gstage[w][j*4+3][l] * a[j].w;
                __builtin_nontemporal_store(o, out4 + qi);
            }
        }
    }
    if (blockIdx.x == 0 && t < (E & 3)) {
        const int e = (E4 << 2) + t;
        out[e] = rnF[col[e]] * attr[e];
    }
}

// ---------------- fallback path (f32, direct atomics) ----------------

__global__ void zero_ws_kernel(float* __restrict__ ws, const int* __restrict__ Np) {
    const int N = *Np;
    const int stride = gridDim.x * blockDim.x;
    for (int i = blockIdx.x * blockDim.x + threadIdx.x; i < N; i += stride)
        ws[i] = 0.0f;
}

__global__ void rowsum_atomic_kernel(const int* __restrict__ row,
                                     const float* __restrict__ attr,
                                     float* __restrict__ rowsum, int E) {
    const int tid = blockIdx.x * blockDim.x + threadIdx.x;
    const int stride = gridDim.x * blockDim.x;
    const int E4 = E >> 2;
    for (int i = tid; i < E4; i += stride) {
        const int4   r = reinterpret_cast<const int4*>(row)[i];
        const float4 a = reinterpret_cast<const float4*>(attr)[i];
        atomicAdd(&rowsum[r.x], a.x);
        atomicAdd(&rowsum[r.y], a.y);
        atomicAdd(&rowsum[r.z], a.z);
        atomicAdd(&rowsum[r.w], a.w);
    }
    for (int i = (E4 << 2) + tid; i < E; i += stride)
        atomicAdd(&rowsum[row[i]], attr[i]);
}

__global__ void recip_fallback_kernel(float* __restrict__ rowsum,
                                      const int* __restrict__ Np) {
    const int N = *Np;
    const int stride = gridDim.x * blockDim.x;
    for (int i = blockIdx.x * blockDim.x + threadIdx.x; i < N; i += stride)
        rowsum[i] = 1.0f / rowsum[i];
}

__global__ __launch_bounds__(256) void gather_scale_f32_kernel(
    const int* __restrict__ col, const float* __restrict__ attr,
    const float* __restrict__ rnorm, float* __restrict__ out, int E)
{
    const int tid = blockIdx.x * blockDim.x + threadIdx.x;
    const int stride = gridDim.x * blockDim.x;
    const int E4 = E >> 2;
    const v4i* col4  = reinterpret_cast<const v4i*>(col);
    const v4f* attr4 = reinterpret_cast<const v4f*>(attr);
    v4f*       out4  = reinterpret_cast<v4f*>(out);
    for (int i = tid; i < E4; i += stride) {
        const v4i c = __builtin_nontemporal_load(col4 + i);
        const v4f a = __builtin_nontemporal_load(attr4 + i);
        v4f o;
        o.x = rnorm[c.x] * a.x; o.y = rnorm[c.y] * a.y;
        o.z = rnorm[c.z] * a.z; o.w = rnorm[c.w] * a.w;
        __builtin_nontemporal_store(o, out4 + i);
    }
    for (int e = (E4 << 2) + tid; e < E; e += stride)
        out[e] = rnorm[col[e]] * attr[e];
}

// ---------------- launch ----------------

extern "C" void kernel_launch(void* const* d_in, const int* in_sizes, int n_in,
                              void* d_out, int out_size, void* d_ws, size_t ws_size,
                              hipStream_t stream) {
    const int*   edge_index = (const int*)d_in[0];     // [2, E]
    const float* edge_attr  = (const float*)d_in[1];   // [E]
    const int*   Np         = (const int*)d_in[2];     // scalar N (device)

    const int E = in_sizes[1];
    const int* row = edge_index;
    const int* col = edge_index + E;
    float* out = (float*)d_out;

    const int nTiles = (E + TILE - 1) / TILE;
    auto align256 = [](size_t x) { return (x + 255) & ~(size_t)255; };

    size_t off = 0;
    const size_t basesOff  = off; off += align256(NB * sizeof(int));
    const size_t totalsOff = off; off += align256(NB * sizeof(int));
    const size_t rnOff     = off; off += align256((size_t)NMAX * sizeof(float)); // 4 MB
    const size_t partOff   = off;
    const size_t histBytes = align256((size_t)nTiles * NB * sizeof(int));
    const size_t scanBytes = 2 * histBytes;                    // histG + offG
    const size_t pairsBytes = ((size_t)E + 2 * NB) * sizeof(ull);

    int nSplit = 0;
    size_t partRegion = 0;
    for (int c : {8, 4, 2, 1}) {
        size_t pr = (size_t)c * NMAX * sizeof(float);
        if (pr < scanBytes) pr = scanBytes;
        if (partOff + pr + pairsBytes <= ws_size) { nSplit = c; partRegion = pr; break; }
    }

    if (nSplit > 0) {
        int*   bases   = (int*)  ((char*)d_ws + basesOff);
        int*   totals  = (int*)  ((char*)d_ws + totalsOff);
        float* rnF     = (float*)((char*)d_ws + rnOff);
        float* partial = (float*)((char*)d_ws + partOff);
        int*   histG   = (int*)  ((char*)d_ws + partOff);             // alias: dead
        int*   offG    = (int*)  ((char*)d_ws + partOff + histBytes); // before reduce
        ull*   pairs   = (ull*)  ((char*)d_ws + partOff + partRegion);

        const int gGroups = ((E >> 2) + 2047) >> 11;

        hist_kernel      <<<nTiles, BLOCK1, 0, stream>>>(row, histG, E);
        totals_kernel    <<<NB, 256, 0, stream>>>(histG, totals, nTiles);
        bases_kernel     <<<1, NB, 0, stream>>>(totals, bases);
        offsets_kernel   <<<NB, 256, 0, stream>>>(histG, bases, offG, nTiles);
        scatter_kernel   <<<nTiles, BLOCK1, 0, stream>>>(row, edge_attr, offG, pairs, E);
        reduce_kernel    <<<NB * nSplit, BLOCK2, 0, stream>>>(pairs, totals, bases, partial, nSplit);
        recip_kernel     <<<1024, 256, 0, stream>>>(partial, rnF, Np, nSplit);
        gather_gld_kernel<<<gGroups, 256, 0, stream>>>(col, edge_attr, rnF, out, E);
    } else {
        float* rowsum = (float*)d_ws;
        const int workE = (E + 3) >> 2;
        int gE = (workE + 255) / 256;
        if (gE > 2048) gE = 2048;
        zero_ws_kernel        <<<2048, 256, 0, stream>>>(rowsum, Np);
        rowsum_atomic_kernel  <<<gE, 256, 0, stream>>>(row, edge_attr, rowsum, E);
        recip_fallback_kernel <<<2048, 256, 0, stream>>>(rowsum, Np);
        gather_scale_f32_kernel<<<2048, 256, 0, stream>>>(col, edge_attr, rowsum, out, E);
    }
}

// Round 13
// 370.538 us; speedup vs baseline: 1.0236x; 1.0236x over previous
//
#include <hip/hip_runtime.h>
#include <stdint.h>

// out[e] = edge_attr[e] / segsum(edge_attr, row)[col[e]]
//
// Counting-sort by 8192-wide node bucket, exact atomic-free scatter offsets
// (round-10 structure, best verified: 339us). Round-13: reduce + gather inner
// loops rebuilt as INLINE-ASM forced-MLP loads — three rounds proved the
// compiler never materializes staged loads (VGPR 8/20/36/56), so each pass ran
// a 1-2-deep latency chain. Asm with explicit early-clobber outputs forces
// 8x dwordx4 (reduce) / 16x dword (gather) in flight per thread.
//   P1 hist / P2 totals / P3 bases / P4 offsets / P5 scatter
//   P6 reduce (asm MLP=8) / P7 recip (f32 table) / P8 gather (asm MLP=16)
// nt hints only on truly-dead streams. Fallback (small ws): direct atomics.

typedef int      v4i __attribute__((ext_vector_type(4)));
typedef float    v4f __attribute__((ext_vector_type(4)));
typedef unsigned v4u __attribute__((ext_vector_type(4)));
using ull = unsigned long long;

#define BKT_BITS 13
#define BKT_W    (1 << BKT_BITS)      // 8192 nodes per bucket
#define NB       128                   // supports N <= 1,048,576
#define NMAX     (NB << BKT_BITS)
#define TILE     4096
#define BLOCK1   512
#define BLOCK2   512

// ---------------- fast path ----------------

__global__ __launch_bounds__(BLOCK1) void hist_kernel(
    const int* __restrict__ row, int* __restrict__ histG, int E)
{
    __shared__ int h[NB];
    const int t = threadIdx.x;
    const long base = (long)blockIdx.x * TILE;
    if (t < NB) h[t] = 0;
    __syncthreads();
    if (base + TILE <= (long)E) {
        #pragma unroll
        for (int k = 0; k < 2; ++k) {
            const long e0 = base + ((long)(k * BLOCK1 + t) << 2);
            const v4i rv = *reinterpret_cast<const v4i*>(row + e0);  // regular: row -> L3 for scatter
            atomicAdd(&h[rv.x >> BKT_BITS], 1);
            atomicAdd(&h[rv.y >> BKT_BITS], 1);
            atomicAdd(&h[rv.z >> BKT_BITS], 1);
            atomicAdd(&h[rv.w >> BKT_BITS], 1);
        }
    } else {
        for (int k = 0; k < 2; ++k) {
            const long e0 = base + ((long)(k * BLOCK1 + t) << 2);
            for (int j = 0; j < 4; ++j)
                if (e0 + j < (long)E) atomicAdd(&h[row[e0 + j] >> BKT_BITS], 1);
        }
    }
    __syncthreads();
    if (t < NB) histG[(size_t)blockIdx.x * NB + t] = h[t];
}

__global__ __launch_bounds__(256) void totals_kernel(
    const int* __restrict__ histG, int* __restrict__ totals, int nTiles)
{
    __shared__ int s[256];
    const int b = blockIdx.x;
    int acc = 0;
    for (int t = threadIdx.x; t < nTiles; t += 256)
        acc += histG[(size_t)t * NB + b];
    s[threadIdx.x] = acc;
    __syncthreads();
    for (int o = 128; o > 0; o >>= 1) {
        if (threadIdx.x < o) s[threadIdx.x] += s[threadIdx.x + o];
        __syncthreads();
    }
    if (threadIdx.x == 0) totals[b] = s[0];
}

__global__ __launch_bounds__(NB) void bases_kernel(
    const int* __restrict__ totals, int* __restrict__ bases)
{
    __shared__ int s[NB];
    const int t = threadIdx.x;
    const int rc = (totals[t] + 1) & ~1;      // even-rounded -> 16B-aligned regions
    s[t] = rc;
    __syncthreads();
    for (int off = 1; off < NB; off <<= 1) {
        const int v = (t >= off) ? s[t - off] : 0;
        __syncthreads();
        s[t] += v;
        __syncthreads();
    }
    bases[t] = s[t] - rc;
}

__global__ __launch_bounds__(256) void offsets_kernel(
    const int* __restrict__ histG, const int* __restrict__ bases,
    int* __restrict__ offG, int nTiles)
{
    __shared__ int s[256];
    const int b = blockIdx.x;
    const int seg = (nTiles + 255) >> 8;
    const int t0 = threadIdx.x * seg;
    int acc = 0;
    for (int k = 0; k < seg; ++k) {
        const int t = t0 + k;
        if (t < nTiles) acc += histG[(size_t)t * NB + b];
    }
    s[threadIdx.x] = acc;
    __syncthreads();
    for (int off = 1; off < 256; off <<= 1) {
        const int v = (threadIdx.x >= off) ? s[threadIdx.x - off] : 0;
        __syncthreads();
        s[threadIdx.x] += v;
        __syncthreads();
    }
    int run = bases[b] + s[threadIdx.x] - acc;     // exclusive base for my segment
    for (int k = 0; k < seg; ++k) {
        const int t = t0 + k;
        if (t < nTiles) {
            offG[(size_t)t * NB + b] = run;
            run += histG[(size_t)t * NB + b];
        }
    }
}

__global__ __launch_bounds__(BLOCK1) void scatter_kernel(
    const int* __restrict__ row, const float* __restrict__ attr,
    const int* __restrict__ offG, ull* __restrict__ pairsG, int E)
{
    __shared__ int cnt[NB];
    __shared__ int scanb[NB];
    __shared__ int gbase[NB];
    __shared__ ull pairs[TILE];                    // 32 KB

    const int  t    = threadIdx.x;
    const long base = (long)blockIdx.x * TILE;
    const bool full = (base + TILE <= (long)E);

    if (t < NB) cnt[t] = 0;
    __syncthreads();

    int r[8]; float a[8]; int rk[8];
    if (full) {
        #pragma unroll
        for (int k = 0; k < 2; ++k) {
            const long e0 = base + ((long)(k * BLOCK1 + t) << 2);
            const v4i rv = *reinterpret_cast<const v4i*>(row + e0);   // L3-hot from hist
            const v4f av = __builtin_nontemporal_load(reinterpret_cast<const v4f*>(attr + e0));
            r[k*4+0]=rv.x; r[k*4+1]=rv.y; r[k*4+2]=rv.z; r[k*4+3]=rv.w;
            a[k*4+0]=av.x; a[k*4+1]=av.y; a[k*4+2]=av.z; a[k*4+3]=av.w;
        }
        #pragma unroll
        for (int i = 0; i < 8; ++i)
            rk[i] = atomicAdd(&cnt[r[i] >> BKT_BITS], 1);
    } else {
        for (int k = 0; k < 2; ++k) {
            const long e0 = base + ((long)(k * BLOCK1 + t) << 2);
            for (int j = 0; j < 4; ++j) {
                const int i = k*4 + j;
                if (e0 + j < (long)E) {
                    r[i] = row[e0 + j]; a[i] = attr[e0 + j];
                    rk[i] = atomicAdd(&cnt[r[i] >> BKT_BITS], 1);
                } else r[i] = -1;
            }
        }
    }
    __syncthreads();

    // wave-0 exclusive scan of the 128 bucket counts (2 bins/lane)
    if (t < 64) {
        const int h0 = cnt[2*t], h1 = cnt[2*t+1];
        const int sum = h0 + h1;
        int x = sum;
        #pragma unroll
        for (int off = 1; off < 64; off <<= 1) {
            const int y = __shfl_up(x, off);
            if (t >= off) x += y;
        }
        const int excl = x - sum;
        scanb[2*t]   = excl;
        scanb[2*t+1] = excl + h0;
    }
    if (t < NB) gbase[t] = offG[(size_t)blockIdx.x * NB + t];   // exact, no atomic
    __syncthreads();

    #pragma unroll
    for (int i = 0; i < 8; ++i)
        if (r[i] >= 0)
            pairs[scanb[r[i] >> BKT_BITS] + rk[i]] =
                ((ull)__float_as_uint(a[i]) << 32) | (unsigned)r[i];
    __syncthreads();

    const int total = full ? TILE : (int)((long)E - base);
    for (int s = t; s < total; s += BLOCK1) {
        const ull p  = pairs[s];
        const int bb = (int)(((unsigned)p) >> BKT_BITS);
        const size_t dst = (size_t)gbase[bb] + (size_t)(s - scanb[bb]);
        pairsG[dst] = p;                           // REGULAR store -> L3 keeps it for reduce
    }
}

// reduce: asm-forced 8x dwordx4 staging (16 pairs / iter / thread, MLP=8)
__global__ __launch_bounds__(BLOCK2) void reduce_kernel(
    const ull* __restrict__ pairsG, const int* __restrict__ totals,
    const int* __restrict__ bases, float* __restrict__ partial, int nSplit)
{
    __shared__ float bins[BKT_W];                  // 32 KB
    const int b = blockIdx.x / nSplit;
    const int q = blockIdx.x % nSplit;
    for (int i = threadIdx.x; i < BKT_W; i += BLOCK2) bins[i] = 0.0f;
    __syncthreads();

    const int cnt = totals[b];
    const ull* src = pairsG + (size_t)bases[b];    // even base -> 16B aligned
    const int Q16 = cnt >> 4;
    for (int i = q * BLOCK2 + threadIdx.x; i < Q16; i += nSplit * BLOCK2) {
        const ull addr = (ull)(src + ((size_t)i << 4));   // 128B per thread-iter
        v4u x0, x1, x2, x3, x4, x5, x6, x7;
        asm volatile(
            "global_load_dwordx4 %0, %8, off\n\t"
            "global_load_dwordx4 %1, %8, off offset:16\n\t"
            "global_load_dwordx4 %2, %8, off offset:32\n\t"
            "global_load_dwordx4 %3, %8, off offset:48\n\t"
            "global_load_dwordx4 %4, %8, off offset:64\n\t"
            "global_load_dwordx4 %5, %8, off offset:80\n\t"
            "global_load_dwordx4 %6, %8, off offset:96\n\t"
            "global_load_dwordx4 %7, %8, off offset:112\n\t"
            "s_waitcnt vmcnt(0)"
            : "=&v"(x0), "=&v"(x1), "=&v"(x2), "=&v"(x3),
              "=&v"(x4), "=&v"(x5), "=&v"(x6), "=&v"(x7)
            : "v"(addr)
            : "memory");
        atomicAdd(&bins[x0.x & (BKT_W-1)], __uint_as_float(x0.y));
        atomicAdd(&bins[x0.z & (BKT_W-1)], __uint_as_float(x0.w));
        atomicAdd(&bins[x1.x & (BKT_W-1)], __uint_as_float(x1.y));
        atomicAdd(&bins[x1.z & (BKT_W-1)], __uint_as_float(x1.w));
        atomicAdd(&bins[x2.x & (BKT_W-1)], __uint_as_float(x2.y));
        atomicAdd(&bins[x2.z & (BKT_W-1)], __uint_as_float(x2.w));
        atomicAdd(&bins[x3.x & (BKT_W-1)], __uint_as_float(x3.y));
        atomicAdd(&bins[x3.z & (BKT_W-1)], __uint_as_float(x3.w));
        atomicAdd(&bins[x4.x & (BKT_W-1)], __uint_as_float(x4.y));
        atomicAdd(&bins[x4.z & (BKT_W-1)], __uint_as_float(x4.w));
        atomicAdd(&bins[x5.x & (BKT_W-1)], __uint_as_float(x5.y));
        atomicAdd(&bins[x5.z & (BKT_W-1)], __uint_as_float(x5.w));
        atomicAdd(&bins[x6.x & (BKT_W-1)], __uint_as_float(x6.y));
        atomicAdd(&bins[x6.z & (BKT_W-1)], __uint_as_float(x6.w));
        atomicAdd(&bins[x7.x & (BKT_W-1)], __uint_as_float(x7.y));
        atomicAdd(&bins[x7.z & (BKT_W-1)], __uint_as_float(x7.w));
    }
    if (q == 0) {                                   // tail (cnt % 16)
        for (int o = (Q16 << 4) + threadIdx.x; o < cnt; o += BLOCK2) {
            const ull p = src[o];
            atomicAdd(&bins[(unsigned)p & (BKT_W-1)], __uint_as_float((unsigned)(p >> 32)));
        }
    }
    __syncthreads();

    float* dst = partial + (size_t)q * NMAX + ((size_t)b << BKT_BITS);
    for (int i = threadIdx.x; i < BKT_W; i += BLOCK2)
        dst[i] = bins[i];
}

__global__ void recip_kernel(const float* __restrict__ partial,
                             float* __restrict__ rnF,
                             const int* __restrict__ Np, int nSplit) {
    const int N = *Np;
    const int stride = gridDim.x * blockDim.x;
    for (int i = blockIdx.x * blockDim.x + threadIdx.x; i < N; i += stride) {
        float s = 0.0f;
        for (int q = 0; q < nSplit; ++q) s += partial[(size_t)q * NMAX + i];
        rnF[i] = 1.0f / s;
    }
}

// gather: asm-forced 16 concurrent random table loads per iteration
__global__ __launch_bounds__(256) void gather_asm_kernel(
    const int* __restrict__ col, const float* __restrict__ attr,
    const float* __restrict__ rnF, float* __restrict__ out, int E)
{
    const int tid = blockIdx.x * blockDim.x + threadIdx.x;
    const int stride = gridDim.x * blockDim.x;
    const int E4 = E >> 2;
    const v4i* col4  = reinterpret_cast<const v4i*>(col);
    const v4f* attr4 = reinterpret_cast<const v4f*>(attr);
    v4f*       out4  = reinterpret_cast<v4f*>(out);

    int i = tid;
    for (; i + 3 * stride < E4; i += 4 * stride) {
        const v4i c0 = __builtin_nontemporal_load(col4 + i);
        const v4i c1 = __builtin_nontemporal_load(col4 + i + stride);
        const v4i c2 = __builtin_nontemporal_load(col4 + i + 2 * stride);
        const v4i c3 = __builtin_nontemporal_load(col4 + i + 3 * stride);
        const v4f a0 = __builtin_nontemporal_load(attr4 + i);
        const v4f a1 = __builtin_nontemporal_load(attr4 + i + stride);
        const v4f a2 = __builtin_nontemporal_load(attr4 + i + 2 * stride);
        const v4f a3 = __builtin_nontemporal_load(attr4 + i + 3 * stride);

        const ull p00 = (ull)(rnF + c0.x), p01 = (ull)(rnF + c0.y),
                  p02 = (ull)(rnF + c0.z), p03 = (ull)(rnF + c0.w),
                  p10 = (ull)(rnF + c1.x), p11 = (ull)(rnF + c1.y),
                  p12 = (ull)(rnF + c1.z), p13 = (ull)(rnF + c1.w),
                  p20 = (ull)(rnF + c2.x), p21 = (ull)(rnF + c2.y),
                  p22 = (ull)(rnF + c2.z), p23 = (ull)(rnF + c2.w),
                  p30 = (ull)(rnF + c3.x), p31 = (ull)(rnF + c3.y),
                  p32 = (ull)(rnF + c3.z), p33 = (ull)(rnF + c3.w);
        float f00, f01, f02, f03, f10, f11, f12, f13,
              f20, f21, f22, f23, f30, f31, f32, f33;
        asm volatile(
            "global_load_dword %0, %16, off\n\t"
            "global_load_dword %1, %17, off\n\t"
            "global_load_dword %2, %18, off\n\t"
            "global_load_dword %3, %19, off\n\t"
            "global_load_dword %4, %20, off\n\t"
            "global_load_dword %5, %21, off\n\t"
            "global_load_dword %6, %22, off\n\t"
            "global_load_dword %7, %23, off\n\t"
            "global_load_dword %8, %24, off\n\t"
            "global_load_dword %9, %25, off\n\t"
            "global_load_dword %10, %26, off\n\t"
            "global_load_dword %11, %27, off\n\t"
            "global_load_dword %12, %28, off\n\t"
            "global_load_dword %13, %29, off\n\t"
            "global_load_dword %14, %30, off\n\t"
            "global_load_dword %15, %31, off\n\t"
            "s_waitcnt vmcnt(0)"
            : "=&v"(f00), "=&v"(f01), "=&v"(f02), "=&v"(f03),
              "=&v"(f10), "=&v"(f11), "=&v"(f12), "=&v"(f13),
              "=&v"(f20), "=&v"(f21), "=&v"(f22), "=&v"(f23),
              "=&v"(f30), "=&v"(f31), "=&v"(f32), "=&v"(f33)
            : "v"(p00), "v"(p01), "v"(p02), "v"(p03),
              "v"(p10), "v"(p11), "v"(p12), "v"(p13),
              "v"(p20), "v"(p21), "v"(p22), "v"(p23),
              "v"(p30), "v"(p31), "v"(p32), "v"(p33)
            : "memory");

        v4f o0, o1, o2, o3;
        o0.x = f00 * a0.x; o0.y = f01 * a0.y; o0.z = f02 * a0.z; o0.w = f03 * a0.w;
        o1.x = f10 * a1.x; o1.y = f11 * a1.y; o1.z = f12 * a1.z; o1.w = f13 * a1.w;
        o2.x = f20 * a2.x; o2.y = f21 * a2.y; o2.z = f22 * a2.z; o2.w = f23 * a2.w;
        o3.x = f30 * a3.x; o3.y = f31 * a3.y; o3.z = f32 * a3.z; o3.w = f33 * a3.w;
        __builtin_nontemporal_store(o0, out4 + i);
        __builtin_nontemporal_store(o1, out4 + i + stride);
        __builtin_nontemporal_store(o2, out4 + i + 2 * stride);
        __builtin_nontemporal_store(o3, out4 + i + 3 * stride);
    }
    for (; i < E4; i += stride) {
        const v4i c = __builtin_nontemporal_load(col4 + i);
        const v4f a = __builtin_nontemporal_load(attr4 + i);
        v4f o;
        o.x = rnF[c.x] * a.x; o.y = rnF[c.y] * a.y;
        o.z = rnF[c.z] * a.z; o.w = rnF[c.w] * a.w;
        __builtin_nontemporal_store(o, out4 + i);
    }
    for (int e = (E4 << 2) + tid; e < E; e += stride)
        out[e] = rnF[col[e]] * attr[e];
}

// ---------------- fallback path (f32, direct atomics) ----------------

__global__ void zero_ws_kernel(float* __restrict__ ws, const int* __restrict__ Np) {
    const int N = *Np;
    const int stride = gridDim.x * blockDim.x;
    for (int i = blockIdx.x * blockDim.x + threadIdx.x; i < N; i += stride)
        ws[i] = 0.0f;
}

__global__ void rowsum_atomic_kernel(const int* __restrict__ row,
                                     const float* __restrict__ attr,
                                     float* __restrict__ rowsum, int E) {
    const int tid = blockIdx.x * blockDim.x + threadIdx.x;
    const int stride = gridDim.x * blockDim.x;
    const int E4 = E >> 2;
    for (int i = tid; i < E4; i += stride) {
        const int4   r = reinterpret_cast<const int4*>(row)[i];
        const float4 a = reinterpret_cast<const float4*>(attr)[i];
        atomicAdd(&rowsum[r.x], a.x);
        atomicAdd(&rowsum[r.y], a.y);
        atomicAdd(&rowsum[r.z], a.z);
        atomicAdd(&rowsum[r.w], a.w);
    }
    for (int i = (E4 << 2) + tid; i < E; i += stride)
        atomicAdd(&rowsum[row[i]], attr[i]);
}

__global__ void recip_fallback_kernel(float* __restrict__ rowsum,
                                      const int* __restrict__ Np) {
    const int N = *Np;
    const int stride = gridDim.x * blockDim.x;
    for (int i = blockIdx.x * blockDim.x + threadIdx.x; i < N; i += stride)
        rowsum[i] = 1.0f / rowsum[i];
}

__global__ __launch_bounds__(256) void gather_scale_f32_kernel(
    const int* __restrict__ col, const float* __restrict__ attr,
    const float* __restrict__ rnorm, float* __restrict__ out, int E)
{
    const int tid = blockIdx.x * blockDim.x + threadIdx.x;
    const int stride = gridDim.x * blockDim.x;
    const int E4 = E >> 2;
    const v4i* col4  = reinterpret_cast<const v4i*>(col);
    const v4f* attr4 = reinterpret_cast<const v4f*>(attr);
    v4f*       out4  = reinterpret_cast<v4f*>(out);
    for (int i = tid; i < E4; i += stride) {
        const v4i c = __builtin_nontemporal_load(col4 + i);
        const v4f a = __builtin_nontemporal_load(attr4 + i);
        v4f o;
        o.x = rnorm[c.x] * a.x; o.y = rnorm[c.y] * a.y;
        o.z = rnorm[c.z] * a.z; o.w = rnorm[c.w] * a.w;
        __builtin_nontemporal_store(o, out4 + i);
    }
    for (int e = (E4 << 2) + tid; e < E; e += stride)
        out[e] = rnorm[col[e]] * attr[e];
}

// ---------------- launch ----------------

extern "C" void kernel_launch(void* const* d_in, const int* in_sizes, int n_in,
                              void* d_out, int out_size, void* d_ws, size_t ws_size,
                              hipStream_t stream) {
    const int*   edge_index = (const int*)d_in[0];     // [2, E]
    const float* edge_attr  = (const float*)d_in[1];   // [E]
    const int*   Np         = (const int*)d_in[2];     // scalar N (device)

    const int E = in_sizes[1];
    const int* row = edge_index;
    const int* col = edge_index + E;
    float* out = (float*)d_out;

    const int nTiles = (E + TILE - 1) / TILE;
    auto align256 = [](size_t x) { return (x + 255) & ~(size_t)255; };

    size_t off = 0;
    const size_t basesOff  = off; off += align256(NB * sizeof(int));
    const size_t totalsOff = off; off += align256(NB * sizeof(int));
    const size_t rnOff     = off; off += align256((size_t)NMAX * sizeof(float)); // 4 MB
    const size_t partOff   = off;
    const size_t histBytes = align256((size_t)nTiles * NB * sizeof(int));
    const size_t scanBytes = 2 * histBytes;                    // histG + offG
    const size_t pairsBytes = ((size_t)E + 2 * NB) * sizeof(ull);

    int nSplit = 0;
    size_t partRegion = 0;
    for (int c : {8, 4, 2, 1}) {
        size_t pr = (size_t)c * NMAX * sizeof(float);
        if (pr < scanBytes) pr = scanBytes;
        if (partOff + pr + pairsBytes <= ws_size) { nSplit = c; partRegion = pr; break; }
    }

    if (nSplit > 0) {
        int*   bases   = (int*)  ((char*)d_ws + basesOff);
        int*   totals  = (int*)  ((char*)d_ws + totalsOff);
        float* rnF     = (float*)((char*)d_ws + rnOff);
        float* partial = (float*)((char*)d_ws + partOff);
        int*   histG   = (int*)  ((char*)d_ws + partOff);             // alias: dead
        int*   offG    = (int*)  ((char*)d_ws + partOff + histBytes); // before reduce
        ull*   pairs   = (ull*)  ((char*)d_ws + partOff + partRegion);

        hist_kernel      <<<nTiles, BLOCK1, 0, stream>>>(row, histG, E);
        totals_kernel    <<<NB, 256, 0, stream>>>(histG, totals, nTiles);
        bases_kernel     <<<1, NB, 0, stream>>>(totals, bases);
        offsets_kernel   <<<NB, 256, 0, stream>>>(histG, bases, offG, nTiles);
        scatter_kernel   <<<nTiles, BLOCK1, 0, stream>>>(row, edge_attr, offG, pairs, E);
        reduce_kernel    <<<NB * nSplit, BLOCK2, 0, stream>>>(pairs, totals, bases, partial, nSplit);
        recip_kernel     <<<1024, 256, 0, stream>>>(partial, rnF, Np, nSplit);
        gather_asm_kernel<<<2048, 256, 0, stream>>>(col, edge_attr, rnF, out, E);
    } else {
        float* rowsum = (float*)d_ws;
        const int workE = (E + 3) >> 2;
        int gE = (workE + 255) / 256;
        if (gE > 2048) gE = 2048;
        zero_ws_kernel        <<<2048, 256, 0, stream>>>(rowsum, Np);
        rowsum_atomic_kernel  <<<gE, 256, 0, stream>>>(row, edge_attr, rowsum, E);
        recip_fallback_kernel <<<2048, 256, 0, stream>>>(rowsum, Np);
        gather_scale_f32_kernel<<<2048, 256, 0, stream>>>(col, edge_attr, rowsum, out, E);
    }
}

// Round 14
// 363.970 us; speedup vs baseline: 1.0420x; 1.0180x over previous
//
#include <hip/hip_runtime.h>
#include <stdint.h>

// out[e] = edge_attr[e] / segsum(edge_attr, row)[col[e]]
//
// Counting-sort by 8192-wide node bucket, exact atomic-free scatter offsets.
// Round-14: reduce rebuilt with WAVE-CONTIGUOUS coalesced loads. Evidence:
// 112us (32B thread stride) vs 131us (128B stride) across 4 reduce variants —
// request density, not MLP, is the lever. New layout: lane l reads 16B at
// chunk + w*512pairs + l*16B (8 lines per wave instr, ideal), MLP=4 via asm
// offsets 0/1024/2048/3072. BLOCK2=1024, nSplit pref 4 (512 blocks = 2/CU).
//   P1 hist / P2 totals / P3 bases / P4 offsets / P5 scatter
//   P6 reduce (coalesced asm MLP=4) / P7 recip / P8 gather (asm MLP=16)
// nt hints only on truly-dead streams. Fallback (small ws): direct atomics.

typedef int      v4i __attribute__((ext_vector_type(4)));
typedef float    v4f __attribute__((ext_vector_type(4)));
typedef unsigned v4u __attribute__((ext_vector_type(4)));
using ull = unsigned long long;

#define BKT_BITS 13
#define BKT_W    (1 << BKT_BITS)      // 8192 nodes per bucket
#define NB       128                   // supports N <= 1,048,576
#define NMAX     (NB << BKT_BITS)
#define TILE     4096
#define BLOCK1   512
#define BLOCK2   1024

// ---------------- fast path ----------------

__global__ __launch_bounds__(BLOCK1) void hist_kernel(
    const int* __restrict__ row, int* __restrict__ histG, int E)
{
    __shared__ int h[NB];
    const int t = threadIdx.x;
    const long base = (long)blockIdx.x * TILE;
    if (t < NB) h[t] = 0;
    __syncthreads();
    if (base + TILE <= (long)E) {
        #pragma unroll
        for (int k = 0; k < 2; ++k) {
            const long e0 = base + ((long)(k * BLOCK1 + t) << 2);
            const v4i rv = *reinterpret_cast<const v4i*>(row + e0);  // regular: row -> L3 for scatter
            atomicAdd(&h[rv.x >> BKT_BITS], 1);
            atomicAdd(&h[rv.y >> BKT_BITS], 1);
            atomicAdd(&h[rv.z >> BKT_BITS], 1);
            atomicAdd(&h[rv.w >> BKT_BITS], 1);
        }
    } else {
        for (int k = 0; k < 2; ++k) {
            const long e0 = base + ((long)(k * BLOCK1 + t) << 2);
            for (int j = 0; j < 4; ++j)
                if (e0 + j < (long)E) atomicAdd(&h[row[e0 + j] >> BKT_BITS], 1);
        }
    }
    __syncthreads();
    if (t < NB) histG[(size_t)blockIdx.x * NB + t] = h[t];
}

__global__ __launch_bounds__(256) void totals_kernel(
    const int* __restrict__ histG, int* __restrict__ totals, int nTiles)
{
    __shared__ int s[256];
    const int b = blockIdx.x;
    int acc = 0;
    for (int t = threadIdx.x; t < nTiles; t += 256)
        acc += histG[(size_t)t * NB + b];
    s[threadIdx.x] = acc;
    __syncthreads();
    for (int o = 128; o > 0; o >>= 1) {
        if (threadIdx.x < o) s[threadIdx.x] += s[threadIdx.x + o];
        __syncthreads();
    }
    if (threadIdx.x == 0) totals[b] = s[0];
}

__global__ __launch_bounds__(NB) void bases_kernel(
    const int* __restrict__ totals, int* __restrict__ bases)
{
    __shared__ int s[NB];
    const int t = threadIdx.x;
    const int rc = (totals[t] + 1) & ~1;      // even-rounded -> 16B-aligned regions
    s[t] = rc;
    __syncthreads();
    for (int off = 1; off < NB; off <<= 1) {
        const int v = (t >= off) ? s[t - off] : 0;
        __syncthreads();
        s[t] += v;
        __syncthreads();
    }
    bases[t] = s[t] - rc;
}

__global__ __launch_bounds__(256) void offsets_kernel(
    const int* __restrict__ histG, const int* __restrict__ bases,
    int* __restrict__ offG, int nTiles)
{
    __shared__ int s[256];
    const int b = blockIdx.x;
    const int seg = (nTiles + 255) >> 8;
    const int t0 = threadIdx.x * seg;
    int acc = 0;
    for (int k = 0; k < seg; ++k) {
        const int t = t0 + k;
        if (t < nTiles) acc += histG[(size_t)t * NB + b];
    }
    s[threadIdx.x] = acc;
    __syncthreads();
    for (int off = 1; off < 256; off <<= 1) {
        const int v = (threadIdx.x >= off) ? s[threadIdx.x - off] : 0;
        __syncthreads();
        s[threadIdx.x] += v;
        __syncthreads();
    }
    int run = bases[b] + s[threadIdx.x] - acc;     // exclusive base for my segment
    for (int k = 0; k < seg; ++k) {
        const int t = t0 + k;
        if (t < nTiles) {
            offG[(size_t)t * NB + b] = run;
            run += histG[(size_t)t * NB + b];
        }
    }
}

__global__ __launch_bounds__(BLOCK1) void scatter_kernel(
    const int* __restrict__ row, const float* __restrict__ attr,
    const int* __restrict__ offG, ull* __restrict__ pairsG, int E)
{
    __shared__ int cnt[NB];
    __shared__ int scanb[NB];
    __shared__ int gbase[NB];
    __shared__ ull pairs[TILE];                    // 32 KB

    const int  t    = threadIdx.x;
    const long base = (long)blockIdx.x * TILE;
    const bool full = (base + TILE <= (long)E);

    if (t < NB) cnt[t] = 0;
    __syncthreads();

    int r[8]; float a[8]; int rk[8];
    if (full) {
        #pragma unroll
        for (int k = 0; k < 2; ++k) {
            const long e0 = base + ((long)(k * BLOCK1 + t) << 2);
            const v4i rv = *reinterpret_cast<const v4i*>(row + e0);   // L3-hot from hist
            const v4f av = __builtin_nontemporal_load(reinterpret_cast<const v4f*>(attr + e0));
            r[k*4+0]=rv.x; r[k*4+1]=rv.y; r[k*4+2]=rv.z; r[k*4+3]=rv.w;
            a[k*4+0]=av.x; a[k*4+1]=av.y; a[k*4+2]=av.z; a[k*4+3]=av.w;
        }
        #pragma unroll
        for (int i = 0; i < 8; ++i)
            rk[i] = atomicAdd(&cnt[r[i] >> BKT_BITS], 1);
    } else {
        for (int k = 0; k < 2; ++k) {
            const long e0 = base + ((long)(k * BLOCK1 + t) << 2);
            for (int j = 0; j < 4; ++j) {
                const int i = k*4 + j;
                if (e0 + j < (long)E) {
                    r[i] = row[e0 + j]; a[i] = attr[e0 + j];
                    rk[i] = atomicAdd(&cnt[r[i] >> BKT_BITS], 1);
                } else r[i] = -1;
            }
        }
    }
    __syncthreads();

    // wave-0 exclusive scan of the 128 bucket counts (2 bins/lane)
    if (t < 64) {
        const int h0 = cnt[2*t], h1 = cnt[2*t+1];
        const int sum = h0 + h1;
        int x = sum;
        #pragma unroll
        for (int off = 1; off < 64; off <<= 1) {
            const int y = __shfl_up(x, off);
            if (t >= off) x += y;
        }
        const int excl = x - sum;
        scanb[2*t]   = excl;
        scanb[2*t+1] = excl + h0;
    }
    if (t < NB) gbase[t] = offG[(size_t)blockIdx.x * NB + t];   // exact, no atomic
    __syncthreads();

    #pragma unroll
    for (int i = 0; i < 8; ++i)
        if (r[i] >= 0)
            pairs[scanb[r[i] >> BKT_BITS] + rk[i]] =
                ((ull)__float_as_uint(a[i]) << 32) | (unsigned)r[i];
    __syncthreads();

    const int total = full ? TILE : (int)((long)E - base);
    for (int s = t; s < total; s += BLOCK1) {
        const ull p  = pairs[s];
        const int bb = (int)(((unsigned)p) >> BKT_BITS);
        const size_t dst = (size_t)gbase[bb] + (size_t)(s - scanb[bb]);
        pairsG[dst] = p;                           // REGULAR store -> L3 keeps it for reduce
    }
}

// reduce: wave-contiguous coalesced loads, asm MLP=4 (offsets 0..3072)
__global__ __launch_bounds__(BLOCK2) void reduce_kernel(
    const ull* __restrict__ pairsG, const int* __restrict__ totals,
    const int* __restrict__ bases, float* __restrict__ partial, int nSplit)
{
    __shared__ float bins[BKT_W];                  // 32 KB
    const int b = blockIdx.x / nSplit;
    const int q = blockIdx.x % nSplit;
    const int t = threadIdx.x, w = t >> 6, l = t & 63;
    for (int i = t; i < BKT_W; i += BLOCK2) bins[i] = 0.0f;
    __syncthreads();

    const int cnt = totals[b];
    const ull* src = pairsG + (size_t)bases[b];    // even base -> 16B aligned
    const int nFull = cnt >> 13;                    // 8192-pair chunks (block-wide)

    for (int c = q; c < nFull; c += nSplit) {
        // wave w owns pairs [c*8192 + w*512, +512); lane l at +2l (16B stride)
        const ull addr = (ull)(src + (((size_t)c << 13) + (w << 9) + (l << 1)));
        v4u x0, x1, x2, x3;
        asm volatile(
            "global_load_dwordx4 %0, %4, off\n\t"
            "global_load_dwordx4 %1, %4, off offset:1024\n\t"
            "global_load_dwordx4 %2, %4, off offset:2048\n\t"
            "global_load_dwordx4 %3, %4, off offset:3072\n\t"
            "s_waitcnt vmcnt(0)"
            : "=&v"(x0), "=&v"(x1), "=&v"(x2), "=&v"(x3)
            : "v"(addr)
            : "memory");
        atomicAdd(&bins[x0.x & (BKT_W-1)], __uint_as_float(x0.y));
        atomicAdd(&bins[x0.z & (BKT_W-1)], __uint_as_float(x0.w));
        atomicAdd(&bins[x1.x & (BKT_W-1)], __uint_as_float(x1.y));
        atomicAdd(&bins[x1.z & (BKT_W-1)], __uint_as_float(x1.w));
        atomicAdd(&bins[x2.x & (BKT_W-1)], __uint_as_float(x2.y));
        atomicAdd(&bins[x2.z & (BKT_W-1)], __uint_as_float(x2.w));
        atomicAdd(&bins[x3.x & (BKT_W-1)], __uint_as_float(x3.y));
        atomicAdd(&bins[x3.z & (BKT_W-1)], __uint_as_float(x3.w));
    }
    if (q == 0) {                                   // tail (cnt % 8192)
        for (int o = (nFull << 13) + t; o < cnt; o += BLOCK2) {
            const ull p = src[o];
            atomicAdd(&bins[(unsigned)p & (BKT_W-1)], __uint_as_float((unsigned)(p >> 32)));
        }
    }
    __syncthreads();

    float* dst = partial + (size_t)q * NMAX + ((size_t)b << BKT_BITS);
    for (int i = t; i < BKT_W; i += BLOCK2)
        dst[i] = bins[i];
}

__global__ void recip_kernel(const float* __restrict__ partial,
                             float* __restrict__ rnF,
                             const int* __restrict__ Np, int nSplit) {
    const int N = *Np;
    const int stride = gridDim.x * blockDim.x;
    for (int i = blockIdx.x * blockDim.x + threadIdx.x; i < N; i += stride) {
        float s = 0.0f;
        for (int q = 0; q < nSplit; ++q) s += partial[(size_t)q * NMAX + i];
        rnF[i] = 1.0f / s;
    }
}

// gather: asm-forced 16 concurrent random table loads per iteration
__global__ __launch_bounds__(256) void gather_asm_kernel(
    const int* __restrict__ col, const float* __restrict__ attr,
    const float* __restrict__ rnF, float* __restrict__ out, int E)
{
    const int tid = blockIdx.x * blockDim.x + threadIdx.x;
    const int stride = gridDim.x * blockDim.x;
    const int E4 = E >> 2;
    const v4i* col4  = reinterpret_cast<const v4i*>(col);
    const v4f* attr4 = reinterpret_cast<const v4f*>(attr);
    v4f*       out4  = reinterpret_cast<v4f*>(out);

    int i = tid;
    for (; i + 3 * stride < E4; i += 4 * stride) {
        const v4i c0 = __builtin_nontemporal_load(col4 + i);
        const v4i c1 = __builtin_nontemporal_load(col4 + i + stride);
        const v4i c2 = __builtin_nontemporal_load(col4 + i + 2 * stride);
        const v4i c3 = __builtin_nontemporal_load(col4 + i + 3 * stride);
        const v4f a0 = __builtin_nontemporal_load(attr4 + i);
        const v4f a1 = __builtin_nontemporal_load(attr4 + i + stride);
        const v4f a2 = __builtin_nontemporal_load(attr4 + i + 2 * stride);
        const v4f a3 = __builtin_nontemporal_load(attr4 + i + 3 * stride);

        const ull p00 = (ull)(rnF + c0.x), p01 = (ull)(rnF + c0.y),
                  p02 = (ull)(rnF + c0.z), p03 = (ull)(rnF + c0.w),
                  p10 = (ull)(rnF + c1.x), p11 = (ull)(rnF + c1.y),
                  p12 = (ull)(rnF + c1.z), p13 = (ull)(rnF + c1.w),
                  p20 = (ull)(rnF + c2.x), p21 = (ull)(rnF + c2.y),
                  p22 = (ull)(rnF + c2.z), p23 = (ull)(rnF + c2.w),
                  p30 = (ull)(rnF + c3.x), p31 = (ull)(rnF + c3.y),
                  p32 = (ull)(rnF + c3.z), p33 = (ull)(rnF + c3.w);
        float f00, f01, f02, f03, f10, f11, f12, f13,
              f20, f21, f22, f23, f30, f31, f32, f33;
        asm volatile(
            "global_load_dword %0, %16, off\n\t"
            "global_load_dword %1, %17, off\n\t"
            "global_load_dword %2, %18, off\n\t"
            "global_load_dword %3, %19, off\n\t"
            "global_load_dword %4, %20, off\n\t"
            "global_load_dword %5, %21, off\n\t"
            "global_load_dword %6, %22, off\n\t"
            "global_load_dword %7, %23, off\n\t"
            "global_load_dword %8, %24, off\n\t"
            "global_load_dword %9, %25, off\n\t"
            "global_load_dword %10, %26, off\n\t"
            "global_load_dword %11, %27, off\n\t"
            "global_load_dword %12, %28, off\n\t"
            "global_load_dword %13, %29, off\n\t"
            "global_load_dword %14, %30, off\n\t"
            "global_load_dword %15, %31, off\n\t"
            "s_waitcnt vmcnt(0)"
            : "=&v"(f00), "=&v"(f01), "=&v"(f02), "=&v"(f03),
              "=&v"(f10), "=&v"(f11), "=&v"(f12), "=&v"(f13),
              "=&v"(f20), "=&v"(f21), "=&v"(f22), "=&v"(f23),
              "=&v"(f30), "=&v"(f31), "=&v"(f32), "=&v"(f33)
            : "v"(p00), "v"(p01), "v"(p02), "v"(p03),
              "v"(p10), "v"(p11), "v"(p12), "v"(p13),
              "v"(p20), "v"(p21), "v"(p22), "v"(p23),
              "v"(p30), "v"(p31), "v"(p32), "v"(p33)
            : "memory");

        v4f o0, o1, o2, o3;
        o0.x = f00 * a0.x; o0.y = f01 * a0.y; o0.z = f02 * a0.z; o0.w = f03 * a0.w;
        o1.x = f10 * a1.x; o1.y = f11 * a1.y; o1.z = f12 * a1.z; o1.w = f13 * a1.w;
        o2.x = f20 * a2.x; o2.y = f21 * a2.y; o2.z = f22 * a2.z; o2.w = f23 * a2.w;
        o3.x = f30 * a3.x; o3.y = f31 * a3.y; o3.z = f32 * a3.z; o3.w = f33 * a3.w;
        __builtin_nontemporal_store(o0, out4 + i);
        __builtin_nontemporal_store(o1, out4 + i + stride);
        __builtin_nontemporal_store(o2, out4 + i + 2 * stride);
        __builtin_nontemporal_store(o3, out4 + i + 3 * stride);
    }
    for (; i < E4; i += stride) {
        const v4i c = __builtin_nontemporal_load(col4 + i);
        const v4f a = __builtin_nontemporal_load(attr4 + i);
        v4f o;
        o.x = rnF[c.x] * a.x; o.y = rnF[c.y] * a.y;
        o.z = rnF[c.z] * a.z; o.w = rnF[c.w] * a.w;
        __builtin_nontemporal_store(o, out4 + i);
    }
    for (int e = (E4 << 2) + tid; e < E; e += stride)
        out[e] = rnF[col[e]] * attr[e];
}

// ---------------- fallback path (f32, direct atomics) ----------------

__global__ void zero_ws_kernel(float* __restrict__ ws, const int* __restrict__ Np) {
    const int N = *Np;
    const int stride = gridDim.x * blockDim.x;
    for (int i = blockIdx.x * blockDim.x + threadIdx.x; i < N; i += stride)
        ws[i] = 0.0f;
}

__global__ void rowsum_atomic_kernel(const int* __restrict__ row,
                                     const float* __restrict__ attr,
                                     float* __restrict__ rowsum, int E) {
    const int tid = blockIdx.x * blockDim.x + threadIdx.x;
    const int stride = gridDim.x * blockDim.x;
    const int E4 = E >> 2;
    for (int i = tid; i < E4; i += stride) {
        const int4   r = reinterpret_cast<const int4*>(row)[i];
        const float4 a = reinterpret_cast<const float4*>(attr)[i];
        atomicAdd(&rowsum[r.x], a.x);
        atomicAdd(&rowsum[r.y], a.y);
        atomicAdd(&rowsum[r.z], a.z);
        atomicAdd(&rowsum[r.w], a.w);
    }
    for (int i = (E4 << 2) + tid; i < E; i += stride)
        atomicAdd(&rowsum[row[i]], attr[i]);
}

__global__ void recip_fallback_kernel(float* __restrict__ rowsum,
                                      const int* __restrict__ Np) {
    const int N = *Np;
    const int stride = gridDim.x * blockDim.x;
    for (int i = blockIdx.x * blockDim.x + threadIdx.x; i < N; i += stride)
        rowsum[i] = 1.0f / rowsum[i];
}

__global__ __launch_bounds__(256) void gather_scale_f32_kernel(
    const int* __restrict__ col, const float* __restrict__ attr,
    const float* __restrict__ rnorm, float* __restrict__ out, int E)
{
    const int tid = blockIdx.x * blockDim.x + threadIdx.x;
    const int stride = gridDim.x * blockDim.x;
    const int E4 = E >> 2;
    const v4i* col4  = reinterpret_cast<const v4i*>(col);
    const v4f* attr4 = reinterpret_cast<const v4f*>(attr);
    v4f*       out4  = reinterpret_cast<v4f*>(out);
    for (int i = tid; i < E4; i += stride) {
        const v4i c = __builtin_nontemporal_load(col4 + i);
        const v4f a = __builtin_nontemporal_load(attr4 + i);
        v4f o;
        o.x = rnorm[c.x] * a.x; o.y = rnorm[c.y] * a.y;
        o.z = rnorm[c.z] * a.z; o.w = rnorm[c.w] * a.w;
        __builtin_nontemporal_store(o, out4 + i);
    }
    for (int e = (E4 << 2) + tid; e < E; e += stride)
        out[e] = rnorm[col[e]] * attr[e];
}

// ---------------- launch ----------------

extern "C" void kernel_launch(void* const* d_in, const int* in_sizes, int n_in,
                              void* d_out, int out_size, void* d_ws, size_t ws_size,
                              hipStream_t stream) {
    const int*   edge_index = (const int*)d_in[0];     // [2, E]
    const float* edge_attr  = (const float*)d_in[1];   // [E]
    const int*   Np         = (const int*)d_in[2];     // scalar N (device)

    const int E = in_sizes[1];
    const int* row = edge_index;
    const int* col = edge_index + E;
    float* out = (float*)d_out;

    const int nTiles = (E + TILE - 1) / TILE;
    auto align256 = [](size_t x) { return (x + 255) & ~(size_t)255; };

    size_t off = 0;
    const size_t basesOff  = off; off += align256(NB * sizeof(int));
    const size_t totalsOff = off; off += align256(NB * sizeof(int));
    const size_t rnOff     = off; off += align256((size_t)NMAX * sizeof(float)); // 4 MB
    const size_t partOff   = off;
    const size_t histBytes = align256((size_t)nTiles * NB * sizeof(int));
    const size_t scanBytes = 2 * histBytes;                    // histG + offG
    const size_t pairsBytes = ((size_t)E + 2 * NB) * sizeof(ull);

    int nSplit = 0;
    size_t partRegion = 0;
    for (int c : {4, 2, 1}) {
        size_t pr = (size_t)c * NMAX * sizeof(float);
        if (pr < scanBytes) pr = scanBytes;
        if (partOff + pr + pairsBytes <= ws_size) { nSplit = c; partRegion = pr; break; }
    }

    if (nSplit > 0) {
        int*   bases   = (int*)  ((char*)d_ws + basesOff);
        int*   totals  = (int*)  ((char*)d_ws + totalsOff);
        float* rnF     = (float*)((char*)d_ws + rnOff);
        float* partial = (float*)((char*)d_ws + partOff);
        int*   histG   = (int*)  ((char*)d_ws + partOff);             // alias: dead
        int*   offG    = (int*)  ((char*)d_ws + partOff + histBytes); // before reduce
        ull*   pairs   = (ull*)  ((char*)d_ws + partOff + partRegion);

        hist_kernel      <<<nTiles, BLOCK1, 0, stream>>>(row, histG, E);
        totals_kernel    <<<NB, 256, 0, stream>>>(histG, totals, nTiles);
        bases_kernel     <<<1, NB, 0, stream>>>(totals, bases);
        offsets_kernel   <<<NB, 256, 0, stream>>>(histG, bases, offG, nTiles);
        scatter_kernel   <<<nTiles, BLOCK1, 0, stream>>>(row, edge_attr, offG, pairs, E);
        reduce_kernel    <<<NB * nSplit, BLOCK2, 0, stream>>>(pairs, totals, bases, partial, nSplit);
        recip_kernel     <<<1024, 256, 0, stream>>>(partial, rnF, Np, nSplit);
        gather_asm_kernel<<<2048, 256, 0, stream>>>(col, edge_attr, rnF, out, E);
    } else {
        float* rowsum = (float*)d_ws;
        const int workE = (E + 3) >> 2;
        int gE = (workE + 255) / 256;
        if (gE > 2048) gE = 2048;
        zero_ws_kernel        <<<2048, 256, 0, stream>>>(rowsum, Np);
        rowsum_atomic_kernel  <<<gE, 256, 0, stream>>>(row, edge_attr, rowsum, E);
        recip_fallback_kernel <<<2048, 256, 0, stream>>>(rowsum, Np);
        gather_scale_f32_kernel<<<2048, 256, 0, stream>>>(col, edge_attr, rowsum, out, E);
    }
}

// Round 15
// 363.869 us; speedup vs baseline: 1.0423x; 1.0003x over previous
//
#include <hip/hip_runtime.h>
#include <stdint.h>

// out[e] = edge_attr[e] / segsum(edge_attr, row)[col[e]]
//
// Counting-sort by 8192-wide node bucket, exact atomic-free scatter offsets.
// Round-14: reduce rebuilt with WAVE-CONTIGUOUS coalesced loads. Evidence:
// 112us (32B thread stride) vs 131us (128B stride) across 4 reduce variants —
// request density, not MLP, is the lever. New layout: lane l reads 16B at
// chunk + w*512pairs + l*16B (8 lines per wave instr, ideal), MLP=4 via asm
// offsets 0/1024/2048/3072. BLOCK2=1024, nSplit pref 4 (512 blocks = 2/CU).
//   P1 hist / P2 totals / P3 bases / P4 offsets / P5 scatter
//   P6 reduce (coalesced asm MLP=4) / P7 recip / P8 gather (asm MLP=16)
// nt hints only on truly-dead streams. Fallback (small ws): direct atomics.

typedef int      v4i __attribute__((ext_vector_type(4)));
typedef float    v4f __attribute__((ext_vector_type(4)));
typedef unsigned v4u __attribute__((ext_vector_type(4)));
using ull = unsigned long long;

#define BKT_BITS 13
#define BKT_W    (1 << BKT_BITS)      // 8192 nodes per bucket
#define NB       128                   // supports N <= 1,048,576
#define NMAX     (NB << BKT_BITS)
#define TILE     4096
#define BLOCK1   512
#define BLOCK2   1024

// ---------------- fast path ----------------

__global__ __launch_bounds__(BLOCK1) void hist_kernel(
    const int* __restrict__ row, int* __restrict__ histG, int E)
{
    __shared__ int h[NB];
    const int t = threadIdx.x;
    const long base = (long)blockIdx.x * TILE;
    if (t < NB) h[t] = 0;
    __syncthreads();
    if (base + TILE <= (long)E) {
        #pragma unroll
        for (int k = 0; k < 2; ++k) {
            const long e0 = base + ((long)(k * BLOCK1 + t) << 2);
            const v4i rv = *reinterpret_cast<const v4i*>(row + e0);  // regular: row -> L3 for scatter
            atomicAdd(&h[rv.x >> BKT_BITS], 1);
            atomicAdd(&h[rv.y >> BKT_BITS], 1);
            atomicAdd(&h[rv.z >> BKT_BITS], 1);
            atomicAdd(&h[rv.w >> BKT_BITS], 1);
        }
    } else {
        for (int k = 0; k < 2; ++k) {
            const long e0 = base + ((long)(k * BLOCK1 + t) << 2);
            for (int j = 0; j < 4; ++j)
                if (e0 + j < (long)E) atomicAdd(&h[row[e0 + j] >> BKT_BITS], 1);
        }
    }
    __syncthreads();
    if (t < NB) histG[(size_t)blockIdx.x * NB + t] = h[t];
}

__global__ __launch_bounds__(256) void totals_kernel(
    const int* __restrict__ histG, int* __restrict__ totals, int nTiles)
{
    __shared__ int s[256];
    const int b = blockIdx.x;
    int acc = 0;
    for (int t = threadIdx.x; t < nTiles; t += 256)
        acc += histG[(size_t)t * NB + b];
    s[threadIdx.x] = acc;
    __syncthreads();
    for (int o = 128; o > 0; o >>= 1) {
        if (threadIdx.x < o) s[threadIdx.x] += s[threadIdx.x + o];
        __syncthreads();
    }
    if (threadIdx.x == 0) totals[b] = s[0];
}

__global__ __launch_bounds__(NB) void bases_kernel(
    const int* __restrict__ totals, int* __restrict__ bases)
{
    __shared__ int s[NB];
    const int t = threadIdx.x;
    const int rc = (totals[t] + 1) & ~1;      // even-rounded -> 16B-aligned regions
    s[t] = rc;
    __syncthreads();
    for (int off = 1; off < NB; off <<= 1) {
        const int v = (t >= off) ? s[t - off] : 0;
        __syncthreads();
        s[t] += v;
        __syncthreads();
    }
    bases[t] = s[t] - rc;
}

__global__ __launch_bounds__(256) void offsets_kernel(
    const int* __restrict__ histG, const int* __restrict__ bases,
    int* __restrict__ offG, int nTiles)
{
    __shared__ int s[256];
    const int b = blockIdx.x;
    const int seg = (nTiles + 255) >> 8;
    const int t0 = threadIdx.x * seg;
    int acc = 0;
    for (int k = 0; k < seg; ++k) {
        const int t = t0 + k;
        if (t < nTiles) acc += histG[(size_t)t * NB + b];
    }
    s[threadIdx.x] = acc;
    __syncthreads();
    for (int off = 1; off < 256; off <<= 1) {
        const int v = (threadIdx.x >= off) ? s[threadIdx.x - off] : 0;
        __syncthreads();
        s[threadIdx.x] += v;
        __syncthreads();
    }
    int run = bases[b] + s[threadIdx.x] - acc;     // exclusive base for my segment
    for (int k = 0; k < seg; ++k) {
        const int t = t0 + k;
        if (t < nTiles) {
            offG[(size_t)t * NB + b] = run;
            run += histG[(size_t)t * NB + b];
        }
    }
}

__global__ __launch_bounds__(BLOCK1) void scatter_kernel(
    const int* __restrict__ row, const float* __restrict__ attr,
    const int* __restrict__ offG, ull* __restrict__ pairsG, int E)
{
    __shared__ int cnt[NB];
    __shared__ int scanb[NB];
    __shared__ int gbase[NB];
    __shared__ ull pairs[TILE];                    // 32 KB

    const int  t    = threadIdx.x;
    const long base = (long)blockIdx.x * TILE;
    const bool full = (base + TILE <= (long)E);

    if (t < NB) cnt[t] = 0;
    __syncthreads();

    int r[8]; float a[8]; int rk[8];
    if (full) {
        #pragma unroll
        for (int k = 0; k < 2; ++k) {
            const long e0 = base + ((long)(k * BLOCK1 + t) << 2);
            const v4i rv = *reinterpret_cast<const v4i*>(row + e0);   // L3-hot from hist
            const v4f av = __builtin_nontemporal_load(reinterpret_cast<const v4f*>(attr + e0));
            r[k*4+0]=rv.x; r[k*4+1]=rv.y; r[k*4+2]=rv.z; r[k*4+3]=rv.w;
            a[k*4+0]=av.x; a[k*4+1]=av.y; a[k*4+2]=av.z; a[k*4+3]=av.w;
        }
        #pragma unroll
        for (int i = 0; i < 8; ++i)
            rk[i] = atomicAdd(&cnt[r[i] >> BKT_BITS], 1);
    } else {
        for (int k = 0; k < 2; ++k) {
            const long e0 = base + ((long)(k * BLOCK1 + t) << 2);
            for (int j = 0; j < 4; ++j) {
                const int i = k*4 + j;
                if (e0 + j < (long)E) {
                    r[i] = row[e0 + j]; a[i] = attr[e0 + j];
                    rk[i] = atomicAdd(&cnt[r[i] >> BKT_BITS], 1);
                } else r[i] = -1;
            }
        }
    }
    __syncthreads();

    // wave-0 exclusive scan of the 128 bucket counts (2 bins/lane)
    if (t < 64) {
        const int h0 = cnt[2*t], h1 = cnt[2*t+1];
        const int sum = h0 + h1;
        int x = sum;
        #pragma unroll
        for (int off = 1; off < 64; off <<= 1) {
            const int y = __shfl_up(x, off);
            if (t >= off) x += y;
        }
        const int excl = x - sum;
        scanb[2*t]   = excl;
        scanb[2*t+1] = excl + h0;
    }
    if (t < NB) gbase[t] = offG[(size_t)blockIdx.x * NB + t];   // exact, no atomic
    __syncthreads();

    #pragma unroll
    for (int i = 0; i < 8; ++i)
        if (r[i] >= 0)
            pairs[scanb[r[i] >> BKT_BITS] + rk[i]] =
                ((ull)__float_as_uint(a[i]) << 32) | (unsigned)r[i];
    __syncthreads();

    const int total = full ? TILE : (int)((long)E - base);
    for (int s = t; s < total; s += BLOCK1) {
        const ull p  = pairs[s];
        const int bb = (int)(((unsigned)p) >> BKT_BITS);
        const size_t dst = (size_t)gbase[bb] + (size_t)(s - scanb[bb]);
        pairsG[dst] = p;                           // REGULAR store -> L3 keeps it for reduce
    }
}

// reduce: wave-contiguous coalesced loads, asm MLP=4 (offsets 0..3072)
__global__ __launch_bounds__(BLOCK2) void reduce_kernel(
    const ull* __restrict__ pairsG, const int* __restrict__ totals,
    const int* __restrict__ bases, float* __restrict__ partial, int nSplit)
{
    __shared__ float bins[BKT_W];                  // 32 KB
    const int b = blockIdx.x / nSplit;
    const int q = blockIdx.x % nSplit;
    const int t = threadIdx.x, w = t >> 6, l = t & 63;
    for (int i = t; i < BKT_W; i += BLOCK2) bins[i] = 0.0f;
    __syncthreads();

    const int cnt = totals[b];
    const ull* src = pairsG + (size_t)bases[b];    // even base -> 16B aligned
    const int nFull = cnt >> 13;                    // 8192-pair chunks (block-wide)

    for (int c = q; c < nFull; c += nSplit) {
        // wave w owns pairs [c*8192 + w*512, +512); lane l at +2l (16B stride)
        const ull addr = (ull)(src + (((size_t)c << 13) + (w << 9) + (l << 1)));
        v4u x0, x1, x2, x3;
        asm volatile(
            "global_load_dwordx4 %0, %4, off\n\t"
            "global_load_dwordx4 %1, %4, off offset:1024\n\t"
            "global_load_dwordx4 %2, %4, off offset:2048\n\t"
            "global_load_dwordx4 %3, %4, off offset:3072\n\t"
            "s_waitcnt vmcnt(0)"
            : "=&v"(x0), "=&v"(x1), "=&v"(x2), "=&v"(x3)
            : "v"(addr)
            : "memory");
        atomicAdd(&bins[x0.x & (BKT_W-1)], __uint_as_float(x0.y));
        atomicAdd(&bins[x0.z & (BKT_W-1)], __uint_as_float(x0.w));
        atomicAdd(&bins[x1.x & (BKT_W-1)], __uint_as_float(x1.y));
        atomicAdd(&bins[x1.z & (BKT_W-1)], __uint_as_float(x1.w));
        atomicAdd(&bins[x2.x & (BKT_W-1)], __uint_as_float(x2.y));
        atomicAdd(&bins[x2.z & (BKT_W-1)], __uint_as_float(x2.w));
        atomicAdd(&bins[x3.x & (BKT_W-1)], __uint_as_float(x3.y));
        atomicAdd(&bins[x3.z & (BKT_W-1)], __uint_as_float(x3.w));
    }
    if (q == 0) {                                   // tail (cnt % 8192)
        for (int o = (nFull << 13) + t; o < cnt; o += BLOCK2) {
            const ull p = src[o];
            atomicAdd(&bins[(unsigned)p & (BKT_W-1)], __uint_as_float((unsigned)(p >> 32)));
        }
    }
    __syncthreads();

    float* dst = partial + (size_t)q * NMAX + ((size_t)b << BKT_BITS);
    for (int i = t; i < BKT_W; i += BLOCK2)
        dst[i] = bins[i];
}

__global__ void recip_kernel(const float* __restrict__ partial,
                             float* __restrict__ rnF,
                             const int* __restrict__ Np, int nSplit) {
    const int N = *Np;
    const int stride = gridDim.x * blockDim.x;
    for (int i = blockIdx.x * blockDim.x + threadIdx.x; i < N; i += stride) {
        float s = 0.0f;
        for (int q = 0; q < nSplit; ++q) s += partial[(size_t)q * NMAX + i];
        rnF[i] = 1.0f / s;
    }
}

// gather: asm-forced 16 concurrent random table loads per iteration
__global__ __launch_bounds__(256) void gather_asm_kernel(
    const int* __restrict__ col, const float* __restrict__ attr,
    const float* __restrict__ rnF, float* __restrict__ out, int E)
{
    const int tid = blockIdx.x * blockDim.x + threadIdx.x;
    const int stride = gridDim.x * blockDim.x;
    const int E4 = E >> 2;
    const v4i* col4  = reinterpret_cast<const v4i*>(col);
    const v4f* attr4 = reinterpret_cast<const v4f*>(attr);
    v4f*       out4  = reinterpret_cast<v4f*>(out);

    int i = tid;
    for (; i + 3 * stride < E4; i += 4 * stride) {
        const v4i c0 = __builtin_nontemporal_load(col4 + i);
        const v4i c1 = __builtin_nontemporal_load(col4 + i + stride);
        const v4i c2 = __builtin_nontemporal_load(col4 + i + 2 * stride);
        const v4i c3 = __builtin_nontemporal_load(col4 + i + 3 * stride);
        const v4f a0 = __builtin_nontemporal_load(attr4 + i);
        const v4f a1 = __builtin_nontemporal_load(attr4 + i + stride);
        const v4f a2 = __builtin_nontemporal_load(attr4 + i + 2 * stride);
        const v4f a3 = __builtin_nontemporal_load(attr4 + i + 3 * stride);

        const ull p00 = (ull)(rnF + c0.x), p01 = (ull)(rnF + c0.y),
                  p02 = (ull)(rnF + c0.z), p03 = (ull)(rnF + c0.w),
                  p10 = (ull)(rnF + c1.x), p11 = (ull)(rnF + c1.y),
                  p12 = (ull)(rnF + c1.z), p13 = (ull)(rnF + c1.w),
                  p20 = (ull)(rnF + c2.x), p21 = (ull)(rnF + c2.y),
                  p22 = (ull)(rnF + c2.z), p23 = (ull)(rnF + c2.w),
                  p30 = (ull)(rnF + c3.x), p31 = (ull)(rnF + c3.y),
                  p32 = (ull)(rnF + c3.z), p33 = (ull)(rnF + c3.w);
        float f00, f01, f02, f03, f10, f11, f12, f13,
              f20, f21, f22, f23, f30, f31, f32, f33;
        asm volatile(
            "global_load_dword %0, %16, off\n\t"
            "global_load_dword %1, %17, off\n\t"
            "global_load_dword %2, %18, off\n\t"
            "global_load_dword %3, %19, off\n\t"
            "global_load_dword %4, %20, off\n\t"
            "global_load_dword %5, %21, off\n\t"
            "global_load_dword %6, %22, off\n\t"
            "global_load_dword %7, %23, off\n\t"
            "global_load_dword %8, %24, off\n\t"
            "global_load_dword %9, %25, off\n\t"
            "global_load_dword %10, %26, off\n\t"
            "global_load_dword %11, %27, off\n\t"
            "global_load_dword %12, %28, off\n\t"
            "global_load_dword %13, %29, off\n\t"
            "global_load_dword %14, %30, off\n\t"
            "global_load_dword %15, %31, off\n\t"
            "s_waitcnt vmcnt(0)"
            : "=&v"(f00), "=&v"(f01), "=&v"(f02), "=&v"(f03),
              "=&v"(f10), "=&v"(f11), "=&v"(f12), "=&v"(f13),
              "=&v"(f20), "=&v"(f21), "=&v"(f22), "=&v"(f23),
              "=&v"(f30), "=&v"(f31), "=&v"(f32), "=&v"(f33)
            : "v"(p00), "v"(p01), "v"(p02), "v"(p03),
              "v"(p10), "v"(p11), "v"(p12), "v"(p13),
              "v"(p20), "v"(p21), "v"(p22), "v"(p23),
              "v"(p30), "v"(p31), "v"(p32), "v"(p33)
            : "memory");

        v4f o0, o1, o2, o3;
        o0.x = f00 * a0.x; o0.y = f01 * a0.y; o0.z = f02 * a0.z; o0.w = f03 * a0.w;
        o1.x = f10 * a1.x; o1.y = f11 * a1.y; o1.z = f12 * a1.z; o1.w = f13 * a1.w;
        o2.x = f20 * a2.x; o2.y = f21 * a2.y; o2.z = f22 * a2.z; o2.w = f23 * a2.w;
        o3.x = f30 * a3.x; o3.y = f31 * a3.y; o3.z = f32 * a3.z; o3.w = f33 * a3.w;
        __builtin_nontemporal_store(o0, out4 + i);
        __builtin_nontemporal_store(o1, out4 + i + stride);
        __builtin_nontemporal_store(o2, out4 + i + 2 * stride);
        __builtin_nontemporal_store(o3, out4 + i + 3 * stride);
    }
    for (; i < E4; i += stride) {
        const v4i c = __builtin_nontemporal_load(col4 + i);
        const v4f a = __builtin_nontemporal_load(attr4 + i);
        v4f o;
        o.x = rnF[c.x] * a.x; o.y = rnF[c.y] * a.y;
        o.z = rnF[c.z] * a.z; o.w = rnF[c.w] * a.w;
        __builtin_nontemporal_store(o, out4 + i);
    }
    for (int e = (E4 << 2) + tid; e < E; e += stride)
        out[e] = rnF[col[e]] * attr[e];
}

// ---------------- fallback path (f32, direct atomics) ----------------

__global__ void zero_ws_kernel(float* __restrict__ ws, const int* __restrict__ Np) {
    const int N = *Np;
    const int stride = gridDim.x * blockDim.x;
    for (int i = blockIdx.x * blockDim.x + threadIdx.x; i < N; i += stride)
        ws[i] = 0.0f;
}

__global__ void rowsum_atomic_kernel(const int* __restrict__ row,
                                     const float* __restrict__ attr,
                                     float* __restrict__ rowsum, int E) {
    const int tid = blockIdx.x * blockDim.x + threadIdx.x;
    const int stride = gridDim.x * blockDim.x;
    const int E4 = E >> 2;
    for (int i = tid; i < E4; i += stride) {
        const int4   r = reinterpret_cast<const int4*>(row)[i];
        const float4 a = reinterpret_cast<const float4*>(attr)[i];
        atomicAdd(&rowsum[r.x], a.x);
        atomicAdd(&rowsum[r.y], a.y);
        atomicAdd(&rowsum[r.z], a.z);
        atomicAdd(&rowsum[r.w], a.w);
    }
    for (int i = (E4 << 2) + tid; i < E; i += stride)
        atomicAdd(&rowsum[row[i]], attr[i]);
}

__global__ void recip_fallback_kernel(float* __restrict__ rowsum,
                                      const int* __restrict__ Np) {
    const int N = *Np;
    const int stride = gridDim.x * blockDim.x;
    for (int i = blockIdx.x * blockDim.x + threadIdx.x; i < N; i += stride)
        rowsum[i] = 1.0f / rowsum[i];
}

__global__ __launch_bounds__(256) void gather_scale_f32_kernel(
    const int* __restrict__ col, const float* __restrict__ attr,
    const float* __restrict__ rnorm, float* __restrict__ out, int E)
{
    const int tid = blockIdx.x * blockDim.x + threadIdx.x;
    const int stride = gridDim.x * blockDim.x;
    const int E4 = E >> 2;
    const v4i* col4  = reinterpret_cast<const v4i*>(col);
    const v4f* attr4 = reinterpret_cast<const v4f*>(attr);
    v4f*       out4  = reinterpret_cast<v4f*>(out);
    for (int i = tid; i < E4; i += stride) {
        const v4i c = __builtin_nontemporal_load(col4 + i);
        const v4f a = __builtin_nontemporal_load(attr4 + i);
        v4f o;
        o.x = rnorm[c.x] * a.x; o.y = rnorm[c.y] * a.y;
        o.z = rnorm[c.z] * a.z; o.w = rnorm[c.w] * a.w;
        __builtin_nontemporal_store(o, out4 + i);
    }
    for (int e = (E4 << 2) + tid; e < E; e += stride)
        out[e] = rnorm[col[e]] * attr[e];
}

// ---------------- launch ----------------

extern "C" void kernel_launch(void* const* d_in, const int* in_sizes, int n_in,
                              void* d_out, int out_size, void* d_ws, size_t ws_size,
                              hipStream_t stream) {
    const int*   edge_index = (const int*)d_in[0];     // [2, E]
    const float* edge_attr  = (const float*)d_in[1];   // [E]
    const int*   Np         = (const int*)d_in[2];     // scalar N (device)

    const int E = in_sizes[1];
    const int* row = edge_index;
    const int* col = edge_index + E;
    float* out = (float*)d_out;

    const int nTiles = (E + TILE - 1) / TILE;
    auto align256 = [](size_t x) { return (x + 255) & ~(size_t)255; };

    size_t off = 0;
    const size_t basesOff  = off; off += align256(NB * sizeof(int));
    const size_t totalsOff = off; off += align256(NB * sizeof(int));
    const size_t rnOff     = off; off += align256((size_t)NMAX * sizeof(float)); // 4 MB
    const size_t partOff   = off;
    const size_t histBytes = align256((size_t)nTiles * NB * sizeof(int));
    const size_t scanBytes = 2 * histBytes;                    // histG + offG
    const size_t pairsBytes = ((size_t)E + 2 * NB) * sizeof(ull);

    int nSplit = 0;
    size_t partRegion = 0;
    for (int c : {4, 2, 1}) {
        size_t pr = (size_t)c * NMAX * sizeof(float);
        if (pr < scanBytes) pr = scanBytes;
        if (partOff + pr + pairsBytes <= ws_size) { nSplit = c; partRegion = pr; break; }
    }

    if (nSplit > 0) {
        int*   bases   = (int*)  ((char*)d_ws + basesOff);
        int*   totals  = (int*)  ((char*)d_ws + totalsOff);
        float* rnF     = (float*)((char*)d_ws + rnOff);
        float* partial = (float*)((char*)d_ws + partOff);
        int*   histG   = (int*)  ((char*)d_ws + partOff);             // alias: dead
        int*   offG    = (int*)  ((char*)d_ws + partOff + histBytes); // before reduce
        ull*   pairs   = (ull*)  ((char*)d_ws + partOff + partRegion);

        hist_kernel      <<<nTiles, BLOCK1, 0, stream>>>(row, histG, E);
        totals_kernel    <<<NB, 256, 0, stream>>>(histG, totals, nTiles);
        bases_kernel     <<<1, NB, 0, stream>>>(totals, bases);
        offsets_kernel   <<<NB, 256, 0, stream>>>(histG, bases, offG, nTiles);
        scatter_kernel   <<<nTiles, BLOCK1, 0, stream>>>(row, edge_attr, offG, pairs, E);
        reduce_kernel    <<<NB * nSplit, BLOCK2, 0, stream>>>(pairs, totals, bases, partial, nSplit);
        recip_kernel     <<<1024, 256, 0, stream>>>(partial, rnF, Np, nSplit);
        gather_asm_kernel<<<2048, 256, 0, stream>>>(col, edge_attr, rnF, out, E);
    } else {
        float* rowsum = (float*)d_ws;
        const int workE = (E + 3) >> 2;
        int gE = (workE + 255) / 256;
        if (gE > 2048) gE = 2048;
        zero_ws_kernel        <<<2048, 256, 0, stream>>>(rowsum, Np);
        rowsum_atomic_kernel  <<<gE, 256, 0, stream>>>(row, edge_attr, rowsum, E);
        recip_fallback_kernel <<<2048, 256, 0, stream>>>(rowsum, Np);
        gather_scale_f32_kernel<<<2048, 256, 0, stream>>>(col, edge_attr, rowsum, out, E);
    }
}

// Round 16
// 362.332 us; speedup vs baseline: 1.0467x; 1.0042x over previous
//
#include <hip/hip_runtime.h>
#include <stdint.h>

// out[e] = edge_attr[e] / segsum(edge_attr, row)[col[e]]
//
// Counting-sort by node bucket, exact atomic-free scatter offsets.
// Round-16: REVERT reduce geometry to round-2's (the only reduce that ran
// ~40us): NB=256 buckets of 4096 nodes, 16KB LDS bins, nSplit=2, plain
// 2x16B loads. Rounds 4-15 all used 8192-wide/32KB-bin geometry and pinned
// at 112-131us across six load-issue variants — geometry, not load issue,
// is the suspect variable. Everything else keeps the proven round-10 form
// (exact offsets, regular stores on pairs, nt only on dead streams,
// asm-MLP=16 gather).

typedef int      v4i __attribute__((ext_vector_type(4)));
typedef float    v4f __attribute__((ext_vector_type(4)));
typedef unsigned v4u __attribute__((ext_vector_type(4)));
using ull = unsigned long long;

#define BKT_BITS 12
#define BKT_W    (1 << BKT_BITS)      // 4096 nodes per bucket
#define NB       256                   // supports N <= 1,048,576
#define NMAX     (NB << BKT_BITS)
#define TILE     4096
#define BLOCK1   512
#define BLOCK2   1024

// ---------------- fast path ----------------

__global__ __launch_bounds__(BLOCK1) void hist_kernel(
    const int* __restrict__ row, int* __restrict__ histG, int E)
{
    __shared__ int h[NB];
    const int t = threadIdx.x;
    const long base = (long)blockIdx.x * TILE;
    if (t < NB) h[t] = 0;
    __syncthreads();
    if (base + TILE <= (long)E) {
        #pragma unroll
        for (int k = 0; k < 2; ++k) {
            const long e0 = base + ((long)(k * BLOCK1 + t) << 2);
            const v4i rv = *reinterpret_cast<const v4i*>(row + e0);  // regular: row -> L3 for scatter
            atomicAdd(&h[rv.x >> BKT_BITS], 1);
            atomicAdd(&h[rv.y >> BKT_BITS], 1);
            atomicAdd(&h[rv.z >> BKT_BITS], 1);
            atomicAdd(&h[rv.w >> BKT_BITS], 1);
        }
    } else {
        for (int k = 0; k < 2; ++k) {
            const long e0 = base + ((long)(k * BLOCK1 + t) << 2);
            for (int j = 0; j < 4; ++j)
                if (e0 + j < (long)E) atomicAdd(&h[row[e0 + j] >> BKT_BITS], 1);
        }
    }
    __syncthreads();
    if (t < NB) histG[(size_t)blockIdx.x * NB + t] = h[t];
}

__global__ __launch_bounds__(256) void totals_kernel(
    const int* __restrict__ histG, int* __restrict__ totals, int nTiles)
{
    __shared__ int s[256];
    const int b = blockIdx.x;
    int acc = 0;
    for (int t = threadIdx.x; t < nTiles; t += 256)
        acc += histG[(size_t)t * NB + b];
    s[threadIdx.x] = acc;
    __syncthreads();
    for (int o = 128; o > 0; o >>= 1) {
        if (threadIdx.x < o) s[threadIdx.x] += s[threadIdx.x + o];
        __syncthreads();
    }
    if (threadIdx.x == 0) totals[b] = s[0];
}

__global__ __launch_bounds__(NB) void bases_kernel(
    const int* __restrict__ totals, int* __restrict__ bases)
{
    __shared__ int s[NB];
    const int t = threadIdx.x;
    const int rc = (totals[t] + 1) & ~1;      // even-rounded -> 16B-aligned regions
    s[t] = rc;
    __syncthreads();
    for (int off = 1; off < NB; off <<= 1) {
        const int v = (t >= off) ? s[t - off] : 0;
        __syncthreads();
        s[t] += v;
        __syncthreads();
    }
    bases[t] = s[t] - rc;
}

__global__ __launch_bounds__(256) void offsets_kernel(
    const int* __restrict__ histG, const int* __restrict__ bases,
    int* __restrict__ offG, int nTiles)
{
    __shared__ int s[256];
    const int b = blockIdx.x;
    const int seg = (nTiles + 255) >> 8;
    const int t0 = threadIdx.x * seg;
    int acc = 0;
    for (int k = 0; k < seg; ++k) {
        const int t = t0 + k;
        if (t < nTiles) acc += histG[(size_t)t * NB + b];
    }
    s[threadIdx.x] = acc;
    __syncthreads();
    for (int off = 1; off < 256; off <<= 1) {
        const int v = (threadIdx.x >= off) ? s[threadIdx.x - off] : 0;
        __syncthreads();
        s[threadIdx.x] += v;
        __syncthreads();
    }
    int run = bases[b] + s[threadIdx.x] - acc;     // exclusive base for my segment
    for (int k = 0; k < seg; ++k) {
        const int t = t0 + k;
        if (t < nTiles) {
            offG[(size_t)t * NB + b] = run;
            run += histG[(size_t)t * NB + b];
        }
    }
}

__global__ __launch_bounds__(BLOCK1) void scatter_kernel(
    const int* __restrict__ row, const float* __restrict__ attr,
    const int* __restrict__ offG, ull* __restrict__ pairsG, int E)
{
    __shared__ int cnt[NB];
    __shared__ int scanb[NB];
    __shared__ int gbase[NB];
    __shared__ ull pairs[TILE];                    // 32 KB

    const int  t    = threadIdx.x;
    const long base = (long)blockIdx.x * TILE;
    const bool full = (base + TILE <= (long)E);

    if (t < NB) cnt[t] = 0;
    __syncthreads();

    int r[8]; float a[8]; int rk[8];
    if (full) {
        #pragma unroll
        for (int k = 0; k < 2; ++k) {
            const long e0 = base + ((long)(k * BLOCK1 + t) << 2);
            const v4i rv = *reinterpret_cast<const v4i*>(row + e0);   // L3-hot from hist
            const v4f av = __builtin_nontemporal_load(reinterpret_cast<const v4f*>(attr + e0));
            r[k*4+0]=rv.x; r[k*4+1]=rv.y; r[k*4+2]=rv.z; r[k*4+3]=rv.w;
            a[k*4+0]=av.x; a[k*4+1]=av.y; a[k*4+2]=av.z; a[k*4+3]=av.w;
        }
        #pragma unroll
        for (int i = 0; i < 8; ++i)
            rk[i] = atomicAdd(&cnt[r[i] >> BKT_BITS], 1);
    } else {
        for (int k = 0; k < 2; ++k) {
            const long e0 = base + ((long)(k * BLOCK1 + t) << 2);
            for (int j = 0; j < 4; ++j) {
                const int i = k*4 + j;
                if (e0 + j < (long)E) {
                    r[i] = row[e0 + j]; a[i] = attr[e0 + j];
                    rk[i] = atomicAdd(&cnt[r[i] >> BKT_BITS], 1);
                } else r[i] = -1;
            }
        }
    }
    __syncthreads();

    // wave-0 exclusive scan of the 256 bucket counts (4 bins/lane)
    if (t < 64) {
        const int h0 = cnt[4*t+0], h1 = cnt[4*t+1], h2 = cnt[4*t+2], h3 = cnt[4*t+3];
        const int sum = h0 + h1 + h2 + h3;
        int x = sum;
        #pragma unroll
        for (int off = 1; off < 64; off <<= 1) {
            const int y = __shfl_up(x, off);
            if (t >= off) x += y;
        }
        const int excl = x - sum;
        scanb[4*t+0] = excl;
        scanb[4*t+1] = excl + h0;
        scanb[4*t+2] = excl + h0 + h1;
        scanb[4*t+3] = excl + h0 + h1 + h2;
    }
    if (t < NB) gbase[t] = offG[(size_t)blockIdx.x * NB + t];   // exact, no atomic
    __syncthreads();

    #pragma unroll
    for (int i = 0; i < 8; ++i)
        if (r[i] >= 0)
            pairs[scanb[r[i] >> BKT_BITS] + rk[i]] =
                ((ull)__float_as_uint(a[i]) << 32) | (unsigned)r[i];
    __syncthreads();

    const int total = full ? TILE : (int)((long)E - base);
    for (int s = t; s < total; s += BLOCK1) {
        const ull p  = pairs[s];
        const int bb = (int)(((unsigned)p) >> BKT_BITS);
        const size_t dst = (size_t)gbase[bb] + (size_t)(s - scanb[bb]);
        pairsG[dst] = p;                           // REGULAR store -> L3 keeps it for reduce
    }
}

// reduce: round-2 geometry — 16KB bins, plain 2x16B loads, nSplit blocks/bucket
__global__ __launch_bounds__(BLOCK2) void reduce_kernel(
    const ull* __restrict__ pairsG, const int* __restrict__ totals,
    const int* __restrict__ bases, float* __restrict__ partial, int nSplit)
{
    __shared__ float bins[BKT_W];                  // 16 KB
    const int b = blockIdx.x / nSplit;
    const int q = blockIdx.x % nSplit;
    for (int i = threadIdx.x; i < BKT_W; i += BLOCK2) bins[i] = 0.0f;
    __syncthreads();

    const int cnt = totals[b];
    const ull* src = pairsG + (size_t)bases[b];    // even base -> 16B aligned
    const int Q = cnt >> 2;                         // 4-pair quads
    for (int i = q * BLOCK2 + threadIdx.x; i < Q; i += nSplit * BLOCK2) {
        const v4u p0 = *reinterpret_cast<const v4u*>(src + 4*(size_t)i);
        const v4u p1 = *reinterpret_cast<const v4u*>(src + 4*(size_t)i + 2);
        atomicAdd(&bins[p0.x & (BKT_W-1)], __uint_as_float(p0.y));
        atomicAdd(&bins[p0.z & (BKT_W-1)], __uint_as_float(p0.w));
        atomicAdd(&bins[p1.x & (BKT_W-1)], __uint_as_float(p1.y));
        atomicAdd(&bins[p1.z & (BKT_W-1)], __uint_as_float(p1.w));
    }
    const int rem = cnt - (Q << 2);
    if (q == 0 && threadIdx.x < rem) {
        const ull p = src[(Q << 2) + threadIdx.x];
        atomicAdd(&bins[(unsigned)p & (BKT_W-1)], __uint_as_float((unsigned)(p >> 32)));
    }
    __syncthreads();

    float* dst = partial + (size_t)q * NMAX + ((size_t)b << BKT_BITS);
    for (int i = threadIdx.x; i < BKT_W; i += BLOCK2)
        dst[i] = bins[i];
}

__global__ void recip_kernel(const float* __restrict__ partial,
                             float* __restrict__ rnF,
                             const int* __restrict__ Np, int nSplit) {
    const int N = *Np;
    const int stride = gridDim.x * blockDim.x;
    for (int i = blockIdx.x * blockDim.x + threadIdx.x; i < N; i += stride) {
        float s = 0.0f;
        for (int q = 0; q < nSplit; ++q) s += partial[(size_t)q * NMAX + i];
        rnF[i] = 1.0f / s;
    }
}

// gather: asm-forced 16 concurrent random table loads per iteration
__global__ __launch_bounds__(256) void gather_asm_kernel(
    const int* __restrict__ col, const float* __restrict__ attr,
    const float* __restrict__ rnF, float* __restrict__ out, int E)
{
    const int tid = blockIdx.x * blockDim.x + threadIdx.x;
    const int stride = gridDim.x * blockDim.x;
    const int E4 = E >> 2;
    const v4i* col4  = reinterpret_cast<const v4i*>(col);
    const v4f* attr4 = reinterpret_cast<const v4f*>(attr);
    v4f*       out4  = reinterpret_cast<v4f*>(out);

    int i = tid;
    for (; i + 3 * stride < E4; i += 4 * stride) {
        const v4i c0 = __builtin_nontemporal_load(col4 + i);
        const v4i c1 = __builtin_nontemporal_load(col4 + i + stride);
        const v4i c2 = __builtin_nontemporal_load(col4 + i + 2 * stride);
        const v4i c3 = __builtin_nontemporal_load(col4 + i + 3 * stride);
        const v4f a0 = __builtin_nontemporal_load(attr4 + i);
        const v4f a1 = __builtin_nontemporal_load(attr4 + i + stride);
        const v4f a2 = __builtin_nontemporal_load(attr4 + i + 2 * stride);
        const v4f a3 = __builtin_nontemporal_load(attr4 + i + 3 * stride);

        const ull p00 = (ull)(rnF + c0.x), p01 = (ull)(rnF + c0.y),
                  p02 = (ull)(rnF + c0.z), p03 = (ull)(rnF + c0.w),
                  p10 = (ull)(rnF + c1.x), p11 = (ull)(rnF + c1.y),
                  p12 = (ull)(rnF + c1.z), p13 = (ull)(rnF + c1.w),
                  p20 = (ull)(rnF + c2.x), p21 = (ull)(rnF + c2.y),
                  p22 = (ull)(rnF + c2.z), p23 = (ull)(rnF + c2.w),
                  p30 = (ull)(rnF + c3.x), p31 = (ull)(rnF + c3.y),
                  p32 = (ull)(rnF + c3.z), p33 = (ull)(rnF + c3.w);
        float f00, f01, f02, f03, f10, f11, f12, f13,
              f20, f21, f22, f23, f30, f31, f32, f33;
        asm volatile(
            "global_load_dword %0, %16, off\n\t"
            "global_load_dword %1, %17, off\n\t"
            "global_load_dword %2, %18, off\n\t"
            "global_load_dword %3, %19, off\n\t"
            "global_load_dword %4, %20, off\n\t"
            "global_load_dword %5, %21, off\n\t"
            "global_load_dword %6, %22, off\n\t"
            "global_load_dword %7, %23, off\n\t"
            "global_load_dword %8, %24, off\n\t"
            "global_load_dword %9, %25, off\n\t"
            "global_load_dword %10, %26, off\n\t"
            "global_load_dword %11, %27, off\n\t"
            "global_load_dword %12, %28, off\n\t"
            "global_load_dword %13, %29, off\n\t"
            "global_load_dword %14, %30, off\n\t"
            "global_load_dword %15, %31, off\n\t"
            "s_waitcnt vmcnt(0)"
            : "=&v"(f00), "=&v"(f01), "=&v"(f02), "=&v"(f03),
              "=&v"(f10), "=&v"(f11), "=&v"(f12), "=&v"(f13),
              "=&v"(f20), "=&v"(f21), "=&v"(f22), "=&v"(f23),
              "=&v"(f30), "=&v"(f31), "=&v"(f32), "=&v"(f33)
            : "v"(p00), "v"(p01), "v"(p02), "v"(p03),
              "v"(p10), "v"(p11), "v"(p12), "v"(p13),
              "v"(p20), "v"(p21), "v"(p22), "v"(p23),
              "v"(p30), "v"(p31), "v"(p32), "v"(p33)
            : "memory");

        v4f o0, o1, o2, o3;
        o0.x = f00 * a0.x; o0.y = f01 * a0.y; o0.z = f02 * a0.z; o0.w = f03 * a0.w;
        o1.x = f10 * a1.x; o1.y = f11 * a1.y; o1.z = f12 * a1.z; o1.w = f13 * a1.w;
        o2.x = f20 * a2.x; o2.y = f21 * a2.y; o2.z = f22 * a2.z; o2.w = f23 * a2.w;
        o3.x = f30 * a3.x; o3.y = f31 * a3.y; o3.z = f32 * a3.z; o3.w = f33 * a3.w;
        __builtin_nontemporal_store(o0, out4 + i);
        __builtin_nontemporal_store(o1, out4 + i + stride);
        __builtin_nontemporal_store(o2, out4 + i + 2 * stride);
        __builtin_nontemporal_store(o3, out4 + i + 3 * stride);
    }
    for (; i < E4; i += stride) {
        const v4i c = __builtin_nontemporal_load(col4 + i);
        const v4f a = __builtin_nontemporal_load(attr4 + i);
        v4f o;
        o.x = rnF[c.x] * a.x; o.y = rnF[c.y] * a.y;
        o.z = rnF[c.z] * a.z; o.w = rnF[c.w] * a.w;
        __builtin_nontemporal_store(o, out4 + i);
    }
    for (int e = (E4 << 2) + tid; e < E; e += stride)
        out[e] = rnF[col[e]] * attr[e];
}

// ---------------- fallback path (f32, direct atomics) ----------------

__global__ void zero_ws_kernel(float* __restrict__ ws, const int* __restrict__ Np) {
    const int N = *Np;
    const int stride = gridDim.x * blockDim.x;
    for (int i = blockIdx.x * blockDim.x + threadIdx.x; i < N; i += stride)
        ws[i] = 0.0f;
}

__global__ void rowsum_atomic_kernel(const int* __restrict__ row,
                                     const float* __restrict__ attr,
                                     float* __restrict__ rowsum, int E) {
    const int tid = blockIdx.x * blockDim.x + threadIdx.x;
    const int stride = gridDim.x * blockDim.x;
    const int E4 = E >> 2;
    for (int i = tid; i < E4; i += stride) {
        const int4   r = reinterpret_cast<const int4*>(row)[i];
        const float4 a = reinterpret_cast<const float4*>(attr)[i];
        atomicAdd(&rowsum[r.x], a.x);
        atomicAdd(&rowsum[r.y], a.y);
        atomicAdd(&rowsum[r.z], a.z);
        atomicAdd(&rowsum[r.w], a.w);
    }
    for (int i = (E4 << 2) + tid; i < E; i += stride)
        atomicAdd(&rowsum[row[i]], attr[i]);
}

__global__ void recip_fallback_kernel(float* __restrict__ rowsum,
                                      const int* __restrict__ Np) {
    const int N = *Np;
    const int stride = gridDim.x * blockDim.x;
    for (int i = blockIdx.x * blockDim.x + threadIdx.x; i < N; i += stride)
        rowsum[i] = 1.0f / rowsum[i];
}

__global__ __launch_bounds__(256) void gather_scale_f32_kernel(
    const int* __restrict__ col, const float* __restrict__ attr,
    const float* __restrict__ rnorm, float* __restrict__ out, int E)
{
    const int tid = blockIdx.x * blockDim.x + threadIdx.x;
    const int stride = gridDim.x * blockDim.x;
    const int E4 = E >> 2;
    const v4i* col4  = reinterpret_cast<const v4i*>(col);
    const v4f* attr4 = reinterpret_cast<const v4f*>(attr);
    v4f*       out4  = reinterpret_cast<v4f*>(out);
    for (int i = tid; i < E4; i += stride) {
        const v4i c = __builtin_nontemporal_load(col4 + i);
        const v4f a = __builtin_nontemporal_load(attr4 + i);
        v4f o;
        o.x = rnorm[c.x] * a.x; o.y = rnorm[c.y] * a.y;
        o.z = rnorm[c.z] * a.z; o.w = rnorm[c.w] * a.w;
        __builtin_nontemporal_store(o, out4 + i);
    }
    for (int e = (E4 << 2) + tid; e < E; e += stride)
        out[e] = rnorm[col[e]] * attr[e];
}

// ---------------- launch ----------------

extern "C" void kernel_launch(void* const* d_in, const int* in_sizes, int n_in,
                              void* d_out, int out_size, void* d_ws, size_t ws_size,
                              hipStream_t stream) {
    const int*   edge_index = (const int*)d_in[0];     // [2, E]
    const float* edge_attr  = (const float*)d_in[1];   // [E]
    const int*   Np         = (const int*)d_in[2];     // scalar N (device)

    const int E = in_sizes[1];
    const int* row = edge_index;
    const int* col = edge_index + E;
    float* out = (float*)d_out;

    const int nTiles = (E + TILE - 1) / TILE;
    auto align256 = [](size_t x) { return (x + 255) & ~(size_t)255; };

    size_t off = 0;
    const size_t basesOff  = off; off += align256(NB * sizeof(int));
    const size_t totalsOff = off; off += align256(NB * sizeof(int));
    const size_t rnOff     = off; off += align256((size_t)NMAX * sizeof(float)); // 4 MB
    const size_t partOff   = off;
    const size_t histBytes = align256((size_t)nTiles * NB * sizeof(int));
    const size_t scanBytes = 2 * histBytes;                    // histG + offG
    const size_t pairsBytes = ((size_t)E + 2 * NB) * sizeof(ull);

    int nSplit = 0;
    size_t partRegion = 0;
    for (int c : {2, 1}) {
        size_t pr = (size_t)c * NMAX * sizeof(float);
        if (pr < scanBytes) pr = scanBytes;
        if (partOff + pr + pairsBytes <= ws_size) { nSplit = c; partRegion = pr; break; }
    }

    if (nSplit > 0) {
        int*   bases   = (int*)  ((char*)d_ws + basesOff);
        int*   totals  = (int*)  ((char*)d_ws + totalsOff);
        float* rnF     = (float*)((char*)d_ws + rnOff);
        float* partial = (float*)((char*)d_ws + partOff);
        int*   histG   = (int*)  ((char*)d_ws + partOff);             // alias: dead
        int*   offG    = (int*)  ((char*)d_ws + partOff + histBytes); // before reduce
        ull*   pairs   = (ull*)  ((char*)d_ws + partOff + partRegion);

        hist_kernel      <<<nTiles, BLOCK1, 0, stream>>>(row, histG, E);
        totals_kernel    <<<NB, 256, 0, stream>>>(histG, totals, nTiles);
        bases_kernel     <<<1, NB, 0, stream>>>(totals, bases);
        offsets_kernel   <<<NB, 256, 0, stream>>>(histG, bases, offG, nTiles);
        scatter_kernel   <<<nTiles, BLOCK1, 0, stream>>>(row, edge_attr, offG, pairs, E);
        reduce_kernel    <<<NB * nSplit, BLOCK2, 0, stream>>>(pairs, totals, bases, partial, nSplit);
        recip_kernel     <<<1024, 256, 0, stream>>>(partial, rnF, Np, nSplit);
        gather_asm_kernel<<<2048, 256, 0, stream>>>(col, edge_attr, rnF, out, E);
    } else {
        float* rowsum = (float*)d_ws;
        const int workE = (E + 3) >> 2;
        int gE = (workE + 255) / 256;
        if (gE > 2048) gE = 2048;
        zero_ws_kernel        <<<2048, 256, 0, stream>>>(rowsum, Np);
        rowsum_atomic_kernel  <<<gE, 256, 0, stream>>>(row, edge_attr, rowsum, E);
        recip_fallback_kernel <<<2048, 256, 0, stream>>>(rowsum, Np);
        gather_scale_f32_kernel<<<2048, 256, 0, stream>>>(col, edge_attr, rowsum, out, E);
    }
}

// Round 17
// 346.092 us; speedup vs baseline: 1.0959x; 1.0469x over previous
//
#include <hip/hip_runtime.h>
#include <hip/hip_fp16.h>
#include <stdint.h>

// out[e] = edge_attr[e] / segsum(edge_attr, row)[col[e]]
//
// Round-17: exact round-10 champion structure (339us) + 4-BYTE PACKED pairs:
// pack = (local_id13 << 16) | f16(attr). Halves the dominant internal stream
// (scatter-write + reduce-read: 320 -> 160 MB) with ONE aligned 4B store per
// edge (round 8's regression was 2 stores incl. a 2B one). f16 attr in the
// rowsum adds <= 2^-11 relative; with the f16 rnorm table predict absmax
// ~0.005 < 0.0127. All else = round 10: nt only on dead streams, regular
// stores on pairs (L3 sink), f16-table gather (best of 4 variants, 112us),
// plain loads in reduce (MLP proven worthless across 7 variants).
//   P1 hist / P2 totals / P3 bases / P4 offsets / P5 scatter(pack4)
//   P6 reduce(pack4) / P7 recip->f16 table / P8 gather(f16)
// Fallback (small ws): direct-atomic f32 version.

typedef int      v4i __attribute__((ext_vector_type(4)));
typedef float    v4f __attribute__((ext_vector_type(4)));
typedef unsigned v4u __attribute__((ext_vector_type(4)));
using ull = unsigned long long;
using u32 = unsigned int;
using u16 = unsigned short;
using u8  = unsigned char;

#define BKT_BITS 13
#define BKT_W    (1 << BKT_BITS)      // 8192 nodes per bucket
#define NB       128                   // supports N <= 1,048,576
#define NMAX     (NB << BKT_BITS)
#define TILE     4096
#define BLOCK1   512
#define BLOCK2   1024

// ---------------- fast path ----------------

__global__ __launch_bounds__(BLOCK1) void hist_kernel(
    const int* __restrict__ row, int* __restrict__ histG, int E)
{
    __shared__ int h[NB];
    const int t = threadIdx.x;
    const long base = (long)blockIdx.x * TILE;
    if (t < NB) h[t] = 0;
    __syncthreads();
    if (base + TILE <= (long)E) {
        #pragma unroll
        for (int k = 0; k < 2; ++k) {
            const long e0 = base + ((long)(k * BLOCK1 + t) << 2);
            const v4i rv = *reinterpret_cast<const v4i*>(row + e0);  // regular: row -> L3 for scatter
            atomicAdd(&h[rv.x >> BKT_BITS], 1);
            atomicAdd(&h[rv.y >> BKT_BITS], 1);
            atomicAdd(&h[rv.z >> BKT_BITS], 1);
            atomicAdd(&h[rv.w >> BKT_BITS], 1);
        }
    } else {
        for (int k = 0; k < 2; ++k) {
            const long e0 = base + ((long)(k * BLOCK1 + t) << 2);
            for (int j = 0; j < 4; ++j)
                if (e0 + j < (long)E) atomicAdd(&h[row[e0 + j] >> BKT_BITS], 1);
        }
    }
    __syncthreads();
    if (t < NB) histG[(size_t)blockIdx.x * NB + t] = h[t];
}

__global__ __launch_bounds__(256) void totals_kernel(
    const int* __restrict__ histG, int* __restrict__ totals, int nTiles)
{
    __shared__ int s[256];
    const int b = blockIdx.x;
    int acc = 0;
    for (int t = threadIdx.x; t < nTiles; t += 256)
        acc += histG[(size_t)t * NB + b];
    s[threadIdx.x] = acc;
    __syncthreads();
    for (int o = 128; o > 0; o >>= 1) {
        if (threadIdx.x < o) s[threadIdx.x] += s[threadIdx.x + o];
        __syncthreads();
    }
    if (threadIdx.x == 0) totals[b] = s[0];
}

__global__ __launch_bounds__(NB) void bases_kernel(
    const int* __restrict__ totals, int* __restrict__ bases)
{
    __shared__ int s[NB];
    const int t = threadIdx.x;
    const int rc = (totals[t] + 3) & ~3;      // 4-rounded -> 16B-aligned u32 regions
    s[t] = rc;
    __syncthreads();
    for (int off = 1; off < NB; off <<= 1) {
        const int v = (t >= off) ? s[t - off] : 0;
        __syncthreads();
        s[t] += v;
        __syncthreads();
    }
    bases[t] = s[t] - rc;
}

__global__ __launch_bounds__(256) void offsets_kernel(
    const int* __restrict__ histG, const int* __restrict__ bases,
    int* __restrict__ offG, int nTiles)
{
    __shared__ int s[256];
    const int b = blockIdx.x;
    const int seg = (nTiles + 255) >> 8;
    const int t0 = threadIdx.x * seg;
    int acc = 0;
    for (int k = 0; k < seg; ++k) {
        const int t = t0 + k;
        if (t < nTiles) acc += histG[(size_t)t * NB + b];
    }
    s[threadIdx.x] = acc;
    __syncthreads();
    for (int off = 1; off < 256; off <<= 1) {
        const int v = (threadIdx.x >= off) ? s[threadIdx.x - off] : 0;
        __syncthreads();
        s[threadIdx.x] += v;
        __syncthreads();
    }
    int run = bases[b] + s[threadIdx.x] - acc;     // exclusive base for my segment
    for (int k = 0; k < seg; ++k) {
        const int t = t0 + k;
        if (t < nTiles) {
            offG[(size_t)t * NB + b] = run;
            run += histG[(size_t)t * NB + b];
        }
    }
}

__global__ __launch_bounds__(BLOCK1) void scatter_kernel(
    const int* __restrict__ row, const float* __restrict__ attr,
    const int* __restrict__ offG, u32* __restrict__ packG, int E)
{
    __shared__ int cnt[NB];
    __shared__ int scanb[NB];
    __shared__ int gbase[NB];
    __shared__ u32 pv[TILE];                       // 16 KB packed payload
    __shared__ u8  pb[TILE];                       // 4 KB bucket idx

    const int  t    = threadIdx.x;
    const long base = (long)blockIdx.x * TILE;
    const bool full = (base + TILE <= (long)E);

    if (t < NB) cnt[t] = 0;
    __syncthreads();

    int r[8]; float a[8]; int rk[8];
    if (full) {
        #pragma unroll
        for (int k = 0; k < 2; ++k) {
            const long e0 = base + ((long)(k * BLOCK1 + t) << 2);
            const v4i rv = *reinterpret_cast<const v4i*>(row + e0);   // L3-hot from hist
            const v4f av = __builtin_nontemporal_load(reinterpret_cast<const v4f*>(attr + e0));
            r[k*4+0]=rv.x; r[k*4+1]=rv.y; r[k*4+2]=rv.z; r[k*4+3]=rv.w;
            a[k*4+0]=av.x; a[k*4+1]=av.y; a[k*4+2]=av.z; a[k*4+3]=av.w;
        }
        #pragma unroll
        for (int i = 0; i < 8; ++i)
            rk[i] = atomicAdd(&cnt[r[i] >> BKT_BITS], 1);
    } else {
        for (int k = 0; k < 2; ++k) {
            const long e0 = base + ((long)(k * BLOCK1 + t) << 2);
            for (int j = 0; j < 4; ++j) {
                const int i = k*4 + j;
                if (e0 + j < (long)E) {
                    r[i] = row[e0 + j]; a[i] = attr[e0 + j];
                    rk[i] = atomicAdd(&cnt[r[i] >> BKT_BITS], 1);
                } else r[i] = -1;
            }
        }
    }
    __syncthreads();

    // wave-0 exclusive scan of the 128 bucket counts (2 bins/lane)
    if (t < 64) {
        const int h0 = cnt[2*t], h1 = cnt[2*t+1];
        const int sum = h0 + h1;
        int x = sum;
        #pragma unroll
        for (int off = 1; off < 64; off <<= 1) {
            const int y = __shfl_up(x, off);
            if (t >= off) x += y;
        }
        const int excl = x - sum;
        scanb[2*t]   = excl;
        scanb[2*t+1] = excl + h0;
    }
    if (t < NB) gbase[t] = offG[(size_t)blockIdx.x * NB + t];   // exact, no atomic
    __syncthreads();

    #pragma unroll
    for (int i = 0; i < 8; ++i) {
        if (r[i] >= 0) {
            const int bb  = r[i] >> BKT_BITS;
            const int pos = scanb[bb] + rk[i];
            const u32 h   = (u32)__half_as_ushort(__float2half(a[i]));
            pv[pos] = ((u32)(r[i] & (BKT_W - 1)) << 16) | h;   // (id13<<16)|f16
            pb[pos] = (u8)bb;
        }
    }
    __syncthreads();

    const int total = full ? TILE : (int)((long)E - base);
    for (int s = t; s < total; s += BLOCK1) {
        const int bb = pb[s];
        const size_t dst = (size_t)gbase[bb] + (size_t)(s - scanb[bb]);
        packG[dst] = pv[s];                        // regular 4B store -> L3 keeps it
    }
}

// reduce: 8 packed edges per iter (2x16B loads), LDS f32 bins
__global__ __launch_bounds__(BLOCK2) void reduce_kernel(
    const u32* __restrict__ packG, const int* __restrict__ totals,
    const int* __restrict__ bases, float* __restrict__ partial, int nSplit)
{
    __shared__ float bins[BKT_W];                  // 32 KB
    const int b = blockIdx.x / nSplit;
    const int q = blockIdx.x % nSplit;
    for (int i = threadIdx.x; i < BKT_W; i += BLOCK2) bins[i] = 0.0f;
    __syncthreads();

    const int cnt = totals[b];
    const u32* src = packG + (size_t)bases[b];     // 4-rounded base -> 16B aligned
    const int Q8 = cnt >> 3;                        // 8-edge groups
    for (int i = q * BLOCK2 + threadIdx.x; i < Q8; i += nSplit * BLOCK2) {
        const v4u p0 = *reinterpret_cast<const v4u*>(src + 8*(size_t)i);
        const v4u p1 = *reinterpret_cast<const v4u*>(src + 8*(size_t)i + 4);
        atomicAdd(&bins[p0.x >> 16], __half2float(__ushort_as_half((u16)p0.x)));
        atomicAdd(&bins[p0.y >> 16], __half2float(__ushort_as_half((u16)p0.y)));
        atomicAdd(&bins[p0.z >> 16], __half2float(__ushort_as_half((u16)p0.z)));
        atomicAdd(&bins[p0.w >> 16], __half2float(__ushort_as_half((u16)p0.w)));
        atomicAdd(&bins[p1.x >> 16], __half2float(__ushort_as_half((u16)p1.x)));
        atomicAdd(&bins[p1.y >> 16], __half2float(__ushort_as_half((u16)p1.y)));
        atomicAdd(&bins[p1.z >> 16], __half2float(__ushort_as_half((u16)p1.z)));
        atomicAdd(&bins[p1.w >> 16], __half2float(__ushort_as_half((u16)p1.w)));
    }
    const int rem = cnt - (Q8 << 3);
    if (q == 0 && threadIdx.x < rem) {
        const u32 p = src[(Q8 << 3) + threadIdx.x];
        atomicAdd(&bins[p >> 16], __half2float(__ushort_as_half((u16)p)));
    }
    __syncthreads();

    float* dst = partial + (size_t)q * NMAX + ((size_t)b << BKT_BITS);
    for (int i = threadIdx.x; i < BKT_W; i += BLOCK2)
        dst[i] = bins[i];
}

__global__ void recip_kernel(const float* __restrict__ partial,
                             __half* __restrict__ rnorm16,
                             const int* __restrict__ Np, int nSplit) {
    const int N = *Np;
    const int stride = gridDim.x * blockDim.x;
    for (int i = blockIdx.x * blockDim.x + threadIdx.x; i < N; i += stride) {
        float s = 0.0f;
        for (int q = 0; q < nSplit; ++q) s += partial[(size_t)q * NMAX + i];
        rnorm16[i] = __float2half(1.0f / s);
    }
}

// ---------------- gather pass (round-10 champion form, f16 table) ----------------

__global__ __launch_bounds__(256) void gather_scale_f16_kernel(
    const int* __restrict__ col, const float* __restrict__ attr,
    const __half* __restrict__ rn, float* __restrict__ out, int E)
{
    const int tid = blockIdx.x * blockDim.x + threadIdx.x;
    const int stride = gridDim.x * blockDim.x;
    const int E4 = E >> 2;
    const v4i* col4  = reinterpret_cast<const v4i*>(col);
    const v4f* attr4 = reinterpret_cast<const v4f*>(attr);
    v4f*       out4  = reinterpret_cast<v4f*>(out);

    int i = tid;
    for (; i + 3 * stride < E4; i += 4 * stride) {       // 16 random loads in flight
        const v4i c0 = __builtin_nontemporal_load(col4 + i);
        const v4i c1 = __builtin_nontemporal_load(col4 + i + stride);
        const v4i c2 = __builtin_nontemporal_load(col4 + i + 2 * stride);
        const v4i c3 = __builtin_nontemporal_load(col4 + i + 3 * stride);
        const v4f a0 = __builtin_nontemporal_load(attr4 + i);
        const v4f a1 = __builtin_nontemporal_load(attr4 + i + stride);
        const v4f a2 = __builtin_nontemporal_load(attr4 + i + 2 * stride);
        const v4f a3 = __builtin_nontemporal_load(attr4 + i + 3 * stride);
        v4f o0, o1, o2, o3;
        o0.x = __half2float(rn[c0.x]) * a0.x; o0.y = __half2float(rn[c0.y]) * a0.y;
        o0.z = __half2float(rn[c0.z]) * a0.z; o0.w = __half2float(rn[c0.w]) * a0.w;
        o1.x = __half2float(rn[c1.x]) * a1.x; o1.y = __half2float(rn[c1.y]) * a1.y;
        o1.z = __half2float(rn[c1.z]) * a1.z; o1.w = __half2float(rn[c1.w]) * a1.w;
        o2.x = __half2float(rn[c2.x]) * a2.x; o2.y = __half2float(rn[c2.y]) * a2.y;
        o2.z = __half2float(rn[c2.z]) * a2.z; o2.w = __half2float(rn[c2.w]) * a2.w;
        o3.x = __half2float(rn[c3.x]) * a3.x; o3.y = __half2float(rn[c3.y]) * a3.y;
        o3.z = __half2float(rn[c3.z]) * a3.z; o3.w = __half2float(rn[c3.w]) * a3.w;
        __builtin_nontemporal_store(o0, out4 + i);
        __builtin_nontemporal_store(o1, out4 + i + stride);
        __builtin_nontemporal_store(o2, out4 + i + 2 * stride);
        __builtin_nontemporal_store(o3, out4 + i + 3 * stride);
    }
    for (; i < E4; i += stride) {
        const v4i c = __builtin_nontemporal_load(col4 + i);
        const v4f a = __builtin_nontemporal_load(attr4 + i);
        v4f o;
        o.x = __half2float(rn[c.x]) * a.x; o.y = __half2float(rn[c.y]) * a.y;
        o.z = __half2float(rn[c.z]) * a.z; o.w = __half2float(rn[c.w]) * a.w;
        __builtin_nontemporal_store(o, out4 + i);
    }
    for (int e = (E4 << 2) + tid; e < E; e += stride)
        out[e] = __half2float(rn[col[e]]) * attr[e];
}

// ---------------- fallback path (f32, direct atomics) ----------------

__global__ void zero_ws_kernel(float* __restrict__ ws, const int* __restrict__ Np) {
    const int N = *Np;
    const int stride = gridDim.x * blockDim.x;
    for (int i = blockIdx.x * blockDim.x + threadIdx.x; i < N; i += stride)
        ws[i] = 0.0f;
}

__global__ void rowsum_atomic_kernel(const int* __restrict__ row,
                                     const float* __restrict__ attr,
                                     float* __restrict__ rowsum, int E) {
    const int tid = blockIdx.x * blockDim.x + threadIdx.x;
    const int stride = gridDim.x * blockDim.x;
    const int E4 = E >> 2;
    for (int i = tid; i < E4; i += stride) {
        const int4   r = reinterpret_cast<const int4*>(row)[i];
        const float4 a = reinterpret_cast<const float4*>(attr)[i];
        atomicAdd(&rowsum[r.x], a.x);
        atomicAdd(&rowsum[r.y], a.y);
        atomicAdd(&rowsum[r.z], a.z);
        atomicAdd(&rowsum[r.w], a.w);
    }
    for (int i = (E4 << 2) + tid; i < E; i += stride)
        atomicAdd(&rowsum[row[i]], attr[i]);
}

__global__ void recip_fallback_kernel(float* __restrict__ rowsum,
                                      const int* __restrict__ Np) {
    const int N = *Np;
    const int stride = gridDim.x * blockDim.x;
    for (int i = blockIdx.x * blockDim.x + threadIdx.x; i < N; i += stride)
        rowsum[i] = 1.0f / rowsum[i];
}

__global__ __launch_bounds__(256) void gather_scale_f32_kernel(
    const int* __restrict__ col, const float* __restrict__ attr,
    const float* __restrict__ rnorm, float* __restrict__ out, int E)
{
    const int tid = blockIdx.x * blockDim.x + threadIdx.x;
    const int stride = gridDim.x * blockDim.x;
    const int E4 = E >> 2;
    const v4i* col4  = reinterpret_cast<const v4i*>(col);
    const v4f* attr4 = reinterpret_cast<const v4f*>(attr);
    v4f*       out4  = reinterpret_cast<v4f*>(out);
    for (int i = tid; i < E4; i += stride) {
        const v4i c = __builtin_nontemporal_load(col4 + i);
        const v4f a = __builtin_nontemporal_load(attr4 + i);
        v4f o;
        o.x = rnorm[c.x] * a.x; o.y = rnorm[c.y] * a.y;
        o.z = rnorm[c.z] * a.z; o.w = rnorm[c.w] * a.w;
        __builtin_nontemporal_store(o, out4 + i);
    }
    for (int e = (E4 << 2) + tid; e < E; e += stride)
        out[e] = rnorm[col[e]] * attr[e];
}

// ---------------- launch ----------------

extern "C" void kernel_launch(void* const* d_in, const int* in_sizes, int n_in,
                              void* d_out, int out_size, void* d_ws, size_t ws_size,
                              hipStream_t stream) {
    const int*   edge_index = (const int*)d_in[0];     // [2, E]
    const float* edge_attr  = (const float*)d_in[1];   // [E]
    const int*   Np         = (const int*)d_in[2];     // scalar N (device)

    const int E = in_sizes[1];
    const int* row = edge_index;
    const int* col = edge_index + E;
    float* out = (float*)d_out;

    const int nTiles = (E + TILE - 1) / TILE;
    auto align256 = [](size_t x) { return (x + 255) & ~(size_t)255; };

    size_t off = 0;
    const size_t basesOff  = off; off += align256(NB * sizeof(int));
    const size_t totalsOff = off; off += align256(NB * sizeof(int));
    const size_t rn16Off   = off; off += align256((size_t)NMAX * sizeof(__half)); // 2 MB
    const size_t partOff   = off;
    const size_t histBytes = align256((size_t)nTiles * NB * sizeof(int));
    const size_t scanBytes = 2 * histBytes;                    // histG + offG
    const size_t packBytes = ((size_t)E + 4 * NB) * sizeof(u32);   // ~80 MB

    int nSplit = 0;
    size_t partRegion = 0;
    for (int c : {8, 4, 2, 1}) {
        size_t pr = (size_t)c * NMAX * sizeof(float);
        if (pr < scanBytes) pr = scanBytes;
        if (partOff + pr + packBytes <= ws_size) { nSplit = c; partRegion = pr; break; }
    }

    if (nSplit > 0) {
        int*    bases   = (int*)   ((char*)d_ws + basesOff);
        int*    totals  = (int*)   ((char*)d_ws + totalsOff);
        __half* rnorm16 = (__half*)((char*)d_ws + rn16Off);
        float*  partial = (float*) ((char*)d_ws + partOff);
        int*    histG   = (int*)   ((char*)d_ws + partOff);             // alias: dead
        int*    offG    = (int*)   ((char*)d_ws + partOff + histBytes); // before reduce
        u32*    pack    = (u32*)   ((char*)d_ws + partOff + partRegion);

        hist_kernel            <<<nTiles, BLOCK1, 0, stream>>>(row, histG, E);
        totals_kernel          <<<NB, 256, 0, stream>>>(histG, totals, nTiles);
        bases_kernel           <<<1, NB, 0, stream>>>(totals, bases);
        offsets_kernel         <<<NB, 256, 0, stream>>>(histG, bases, offG, nTiles);
        scatter_kernel         <<<nTiles, BLOCK1, 0, stream>>>(row, edge_attr, offG, pack, E);
        reduce_kernel          <<<NB * nSplit, BLOCK2, 0, stream>>>(pack, totals, bases, partial, nSplit);
        recip_kernel           <<<1024, 256, 0, stream>>>(partial, rnorm16, Np, nSplit);
        gather_scale_f16_kernel<<<2048, 256, 0, stream>>>(col, edge_attr, rnorm16, out, E);
    } else {
        float* rowsum = (float*)d_ws;
        const int workE = (E + 3) >> 2;
        int gE = (workE + 255) / 256;
        if (gE > 2048) gE = 2048;
        zero_ws_kernel         <<<2048, 256, 0, stream>>>(rowsum, Np);
        rowsum_atomic_kernel   <<<gE, 256, 0, stream>>>(row, edge_attr, rowsum, E);
        recip_fallback_kernel  <<<2048, 256, 0, stream>>>(rowsum, Np);
        gather_scale_f32_kernel<<<2048, 256, 0, stream>>>(col, edge_attr, rowsum, out, E);
    }
}

// Round 18
// 331.019 us; speedup vs baseline: 1.1458x; 1.0455x over previous
//
#include <hip/hip_runtime.h>
#include <hip/hip_fp16.h>
#include <stdint.h>

// out[e] = edge_attr[e] / segsum(edge_attr, row)[col[e]]
//
// Round-18: EXACT round-10 champion (339us, best of 17 rounds) with one
// isolated probe: reduce nSplit=2 (512 blocks = 2/CU, ONE residency round,
// ~10 loop trips/thread vs 2.5, partials 32->8MB). Ledger: reduce pinned at
// 112-131us across 8 variants (bytes/MLP/coalescing/geometry all null) ->
// scattered-request rate is the floor; this is the last untested parameter.
//   P1 hist / P2 totals / P3 bases / P4 offsets / P5 scatter (8B pairs)
//   P6 reduce (nSplit=2) / P7 recip -> f16 table / P8 gather (f16, 4x unroll)
// nt hints only on truly-dead streams. Fallback (small ws): direct atomics.

typedef int      v4i __attribute__((ext_vector_type(4)));
typedef float    v4f __attribute__((ext_vector_type(4)));
typedef unsigned v4u __attribute__((ext_vector_type(4)));
using ull = unsigned long long;

#define BKT_BITS 13
#define BKT_W    (1 << BKT_BITS)      // 8192 nodes per bucket
#define NB       128                   // supports N <= 1,048,576
#define NMAX     (NB << BKT_BITS)
#define TILE     4096
#define BLOCK1   512
#define BLOCK2   1024

// ---------------- fast path ----------------

__global__ __launch_bounds__(BLOCK1) void hist_kernel(
    const int* __restrict__ row, int* __restrict__ histG, int E)
{
    __shared__ int h[NB];
    const int t = threadIdx.x;
    const long base = (long)blockIdx.x * TILE;
    if (t < NB) h[t] = 0;
    __syncthreads();
    if (base + TILE <= (long)E) {
        #pragma unroll
        for (int k = 0; k < 2; ++k) {
            const long e0 = base + ((long)(k * BLOCK1 + t) << 2);
            const v4i rv = *reinterpret_cast<const v4i*>(row + e0);  // regular: row -> L3 for scatter
            atomicAdd(&h[rv.x >> BKT_BITS], 1);
            atomicAdd(&h[rv.y >> BKT_BITS], 1);
            atomicAdd(&h[rv.z >> BKT_BITS], 1);
            atomicAdd(&h[rv.w >> BKT_BITS], 1);
        }
    } else {
        for (int k = 0; k < 2; ++k) {
            const long e0 = base + ((long)(k * BLOCK1 + t) << 2);
            for (int j = 0; j < 4; ++j)
                if (e0 + j < (long)E) atomicAdd(&h[row[e0 + j] >> BKT_BITS], 1);
        }
    }
    __syncthreads();
    if (t < NB) histG[(size_t)blockIdx.x * NB + t] = h[t];
}

__global__ __launch_bounds__(256) void totals_kernel(
    const int* __restrict__ histG, int* __restrict__ totals, int nTiles)
{
    __shared__ int s[256];
    const int b = blockIdx.x;
    int acc = 0;
    for (int t = threadIdx.x; t < nTiles; t += 256)
        acc += histG[(size_t)t * NB + b];
    s[threadIdx.x] = acc;
    __syncthreads();
    for (int o = 128; o > 0; o >>= 1) {
        if (threadIdx.x < o) s[threadIdx.x] += s[threadIdx.x + o];
        __syncthreads();
    }
    if (threadIdx.x == 0) totals[b] = s[0];
}

__global__ __launch_bounds__(NB) void bases_kernel(
    const int* __restrict__ totals, int* __restrict__ bases)
{
    __shared__ int s[NB];
    const int t = threadIdx.x;
    const int rc = (totals[t] + 1) & ~1;      // even-rounded -> 16B-aligned regions
    s[t] = rc;
    __syncthreads();
    for (int off = 1; off < NB; off <<= 1) {
        const int v = (t >= off) ? s[t - off] : 0;
        __syncthreads();
        s[t] += v;
        __syncthreads();
    }
    bases[t] = s[t] - rc;
}

__global__ __launch_bounds__(256) void offsets_kernel(
    const int* __restrict__ histG, const int* __restrict__ bases,
    int* __restrict__ offG, int nTiles)
{
    __shared__ int s[256];
    const int b = blockIdx.x;
    const int seg = (nTiles + 255) >> 8;
    const int t0 = threadIdx.x * seg;
    int acc = 0;
    for (int k = 0; k < seg; ++k) {
        const int t = t0 + k;
        if (t < nTiles) acc += histG[(size_t)t * NB + b];
    }
    s[threadIdx.x] = acc;
    __syncthreads();
    for (int off = 1; off < 256; off <<= 1) {
        const int v = (threadIdx.x >= off) ? s[threadIdx.x - off] : 0;
        __syncthreads();
        s[threadIdx.x] += v;
        __syncthreads();
    }
    int run = bases[b] + s[threadIdx.x] - acc;     // exclusive base for my segment
    for (int k = 0; k < seg; ++k) {
        const int t = t0 + k;
        if (t < nTiles) {
            offG[(size_t)t * NB + b] = run;
            run += histG[(size_t)t * NB + b];
        }
    }
}

__global__ __launch_bounds__(BLOCK1) void scatter_kernel(
    const int* __restrict__ row, const float* __restrict__ attr,
    const int* __restrict__ offG, ull* __restrict__ pairsG, int E)
{
    __shared__ int cnt[NB];
    __shared__ int scanb[NB];
    __shared__ int gbase[NB];
    __shared__ ull pairs[TILE];                    // 32 KB

    const int  t    = threadIdx.x;
    const long base = (long)blockIdx.x * TILE;
    const bool full = (base + TILE <= (long)E);

    if (t < NB) cnt[t] = 0;
    __syncthreads();

    int r[8]; float a[8]; int rk[8];
    if (full) {
        #pragma unroll
        for (int k = 0; k < 2; ++k) {
            const long e0 = base + ((long)(k * BLOCK1 + t) << 2);
            const v4i rv = *reinterpret_cast<const v4i*>(row + e0);   // L3-hot from hist
            const v4f av = __builtin_nontemporal_load(reinterpret_cast<const v4f*>(attr + e0));
            r[k*4+0]=rv.x; r[k*4+1]=rv.y; r[k*4+2]=rv.z; r[k*4+3]=rv.w;
            a[k*4+0]=av.x; a[k*4+1]=av.y; a[k*4+2]=av.z; a[k*4+3]=av.w;
        }
        #pragma unroll
        for (int i = 0; i < 8; ++i)
            rk[i] = atomicAdd(&cnt[r[i] >> BKT_BITS], 1);
    } else {
        for (int k = 0; k < 2; ++k) {
            const long e0 = base + ((long)(k * BLOCK1 + t) << 2);
            for (int j = 0; j < 4; ++j) {
                const int i = k*4 + j;
                if (e0 + j < (long)E) {
                    r[i] = row[e0 + j]; a[i] = attr[e0 + j];
                    rk[i] = atomicAdd(&cnt[r[i] >> BKT_BITS], 1);
                } else r[i] = -1;
            }
        }
    }
    __syncthreads();

    // wave-0 exclusive scan of the 128 bucket counts (2 bins/lane)
    if (t < 64) {
        const int h0 = cnt[2*t], h1 = cnt[2*t+1];
        const int sum = h0 + h1;
        int x = sum;
        #pragma unroll
        for (int off = 1; off < 64; off <<= 1) {
            const int y = __shfl_up(x, off);
            if (t >= off) x += y;
        }
        const int excl = x - sum;
        scanb[2*t]   = excl;
        scanb[2*t+1] = excl + h0;
    }
    if (t < NB) gbase[t] = offG[(size_t)blockIdx.x * NB + t];   // exact, no atomic
    __syncthreads();

    #pragma unroll
    for (int i = 0; i < 8; ++i)
        if (r[i] >= 0)
            pairs[scanb[r[i] >> BKT_BITS] + rk[i]] =
                ((ull)__float_as_uint(a[i]) << 32) | (unsigned)r[i];
    __syncthreads();

    const int total = full ? TILE : (int)((long)E - base);
    for (int s = t; s < total; s += BLOCK1) {
        const ull p  = pairs[s];
        const int bb = (int)(((unsigned)p) >> BKT_BITS);
        const size_t dst = (size_t)gbase[bb] + (size_t)(s - scanb[bb]);
        pairsG[dst] = p;                           // REGULAR store -> L3 keeps it for reduce
    }
}

__global__ __launch_bounds__(BLOCK2) void reduce_kernel(
    const ull* __restrict__ pairsG, const int* __restrict__ totals,
    const int* __restrict__ bases, float* __restrict__ partial, int nSplit)
{
    __shared__ float bins[BKT_W];                  // 32 KB
    const int b = blockIdx.x / nSplit;
    const int q = blockIdx.x % nSplit;
    for (int i = threadIdx.x; i < BKT_W; i += BLOCK2) bins[i] = 0.0f;
    __syncthreads();

    const int cnt = totals[b];
    const ull* src = pairsG + (size_t)bases[b];    // even base -> 16B aligned
    const int Q = cnt >> 2;
    for (int i = q * BLOCK2 + threadIdx.x; i < Q; i += nSplit * BLOCK2) {
        const v4u p0 = *reinterpret_cast<const v4u*>(src + 4*(size_t)i);      // L3-hot
        const v4u p1 = *reinterpret_cast<const v4u*>(src + 4*(size_t)i + 2);
        atomicAdd(&bins[p0.x & (BKT_W-1)], __uint_as_float(p0.y));
        atomicAdd(&bins[p0.z & (BKT_W-1)], __uint_as_float(p0.w));
        atomicAdd(&bins[p1.x & (BKT_W-1)], __uint_as_float(p1.y));
        atomicAdd(&bins[p1.z & (BKT_W-1)], __uint_as_float(p1.w));
    }
    const int rem = cnt - (Q << 2);
    if (q == 0 && threadIdx.x < rem) {
        const ull p = src[(Q << 2) + threadIdx.x];
        atomicAdd(&bins[(unsigned)p & (BKT_W-1)], __uint_as_float((unsigned)(p >> 32)));
    }
    __syncthreads();

    float* dst = partial + (size_t)q * NMAX + ((size_t)b << BKT_BITS);
    for (int i = threadIdx.x; i < BKT_W; i += BLOCK2)
        dst[i] = bins[i];
}

__global__ void recip_kernel(const float* __restrict__ partial,
                             __half* __restrict__ rnorm16,
                             const int* __restrict__ Np, int nSplit) {
    const int N = *Np;
    const int stride = gridDim.x * blockDim.x;
    for (int i = blockIdx.x * blockDim.x + threadIdx.x; i < N; i += stride) {
        float s = 0.0f;
        for (int q = 0; q < nSplit; ++q) s += partial[(size_t)q * NMAX + i];
        rnorm16[i] = __float2half(1.0f / s);
    }
}

// ---------------- gather pass (f16 table, 4x unroll — champion form) ----------------

__global__ __launch_bounds__(256) void gather_scale_f16_kernel(
    const int* __restrict__ col, const float* __restrict__ attr,
    const __half* __restrict__ rn, float* __restrict__ out, int E)
{
    const int tid = blockIdx.x * blockDim.x + threadIdx.x;
    const int stride = gridDim.x * blockDim.x;
    const int E4 = E >> 2;
    const v4i* col4  = reinterpret_cast<const v4i*>(col);
    const v4f* attr4 = reinterpret_cast<const v4f*>(attr);
    v4f*       out4  = reinterpret_cast<v4f*>(out);

    int i = tid;
    for (; i + 3 * stride < E4; i += 4 * stride) {       // 16 random loads in flight
        const v4i c0 = __builtin_nontemporal_load(col4 + i);
        const v4i c1 = __builtin_nontemporal_load(col4 + i + stride);
        const v4i c2 = __builtin_nontemporal_load(col4 + i + 2 * stride);
        const v4i c3 = __builtin_nontemporal_load(col4 + i + 3 * stride);
        const v4f a0 = __builtin_nontemporal_load(attr4 + i);
        const v4f a1 = __builtin_nontemporal_load(attr4 + i + stride);
        const v4f a2 = __builtin_nontemporal_load(attr4 + i + 2 * stride);
        const v4f a3 = __builtin_nontemporal_load(attr4 + i + 3 * stride);
        v4f o0, o1, o2, o3;
        o0.x = __half2float(rn[c0.x]) * a0.x; o0.y = __half2float(rn[c0.y]) * a0.y;
        o0.z = __half2float(rn[c0.z]) * a0.z; o0.w = __half2float(rn[c0.w]) * a0.w;
        o1.x = __half2float(rn[c1.x]) * a1.x; o1.y = __half2float(rn[c1.y]) * a1.y;
        o1.z = __half2float(rn[c1.z]) * a1.z; o1.w = __half2float(rn[c1.w]) * a1.w;
        o2.x = __half2float(rn[c2.x]) * a2.x; o2.y = __half2float(rn[c2.y]) * a2.y;
        o2.z = __half2float(rn[c2.z]) * a2.z; o2.w = __half2float(rn[c2.w]) * a2.w;
        o3.x = __half2float(rn[c3.x]) * a3.x; o3.y = __half2float(rn[c3.y]) * a3.y;
        o3.z = __half2float(rn[c3.z]) * a3.z; o3.w = __half2float(rn[c3.w]) * a3.w;
        __builtin_nontemporal_store(o0, out4 + i);
        __builtin_nontemporal_store(o1, out4 + i + stride);
        __builtin_nontemporal_store(o2, out4 + i + 2 * stride);
        __builtin_nontemporal_store(o3, out4 + i + 3 * stride);
    }
    for (; i < E4; i += stride) {
        const v4i c = __builtin_nontemporal_load(col4 + i);
        const v4f a = __builtin_nontemporal_load(attr4 + i);
        v4f o;
        o.x = __half2float(rn[c.x]) * a.x; o.y = __half2float(rn[c.y]) * a.y;
        o.z = __half2float(rn[c.z]) * a.z; o.w = __half2float(rn[c.w]) * a.w;
        __builtin_nontemporal_store(o, out4 + i);
    }
    for (int e = (E4 << 2) + tid; e < E; e += stride)
        out[e] = __half2float(rn[col[e]]) * attr[e];
}

// ---------------- fallback path (f32, direct atomics) ----------------

__global__ void zero_ws_kernel(float* __restrict__ ws, const int* __restrict__ Np) {
    const int N = *Np;
    const int stride = gridDim.x * blockDim.x;
    for (int i = blockIdx.x * blockDim.x + threadIdx.x; i < N; i += stride)
        ws[i] = 0.0f;
}

__global__ void rowsum_atomic_kernel(const int* __restrict__ row,
                                     const float* __restrict__ attr,
                                     float* __restrict__ rowsum, int E) {
    const int tid = blockIdx.x * blockDim.x + threadIdx.x;
    const int stride = gridDim.x * blockDim.x;
    const int E4 = E >> 2;
    for (int i = tid; i < E4; i += stride) {
        const int4   r = reinterpret_cast<const int4*>(row)[i];
        const float4 a = reinterpret_cast<const float4*>(attr)[i];
        atomicAdd(&rowsum[r.x], a.x);
        atomicAdd(&rowsum[r.y], a.y);
        atomicAdd(&rowsum[r.z], a.z);
        atomicAdd(&rowsum[r.w], a.w);
    }
    for (int i = (E4 << 2) + tid; i < E; i += stride)
        atomicAdd(&rowsum[row[i]], attr[i]);
}

__global__ void recip_fallback_kernel(float* __restrict__ rowsum,
                                      const int* __restrict__ Np) {
    const int N = *Np;
    const int stride = gridDim.x * blockDim.x;
    for (int i = blockIdx.x * blockDim.x + threadIdx.x; i < N; i += stride)
        rowsum[i] = 1.0f / rowsum[i];
}

__global__ __launch_bounds__(256) void gather_scale_f32_kernel(
    const int* __restrict__ col, const float* __restrict__ attr,
    const float* __restrict__ rnorm, float* __restrict__ out, int E)
{
    const int tid = blockIdx.x * blockDim.x + threadIdx.x;
    const int stride = gridDim.x * blockDim.x;
    const int E4 = E >> 2;
    const v4i* col4  = reinterpret_cast<const v4i*>(col);
    const v4f* attr4 = reinterpret_cast<const v4f*>(attr);
    v4f*       out4  = reinterpret_cast<v4f*>(out);
    for (int i = tid; i < E4; i += stride) {
        const v4i c = __builtin_nontemporal_load(col4 + i);
        const v4f a = __builtin_nontemporal_load(attr4 + i);
        v4f o;
        o.x = rnorm[c.x] * a.x; o.y = rnorm[c.y] * a.y;
        o.z = rnorm[c.z] * a.z; o.w = rnorm[c.w] * a.w;
        __builtin_nontemporal_store(o, out4 + i);
    }
    for (int e = (E4 << 2) + tid; e < E; e += stride)
        out[e] = rnorm[col[e]] * attr[e];
}

// ---------------- launch ----------------

extern "C" void kernel_launch(void* const* d_in, const int* in_sizes, int n_in,
                              void* d_out, int out_size, void* d_ws, size_t ws_size,
                              hipStream_t stream) {
    const int*   edge_index = (const int*)d_in[0];     // [2, E]
    const float* edge_attr  = (const float*)d_in[1];   // [E]
    const int*   Np         = (const int*)d_in[2];     // scalar N (device)

    const int E = in_sizes[1];
    const int* row = edge_index;
    const int* col = edge_index + E;
    float* out = (float*)d_out;

    const int nTiles = (E + TILE - 1) / TILE;
    auto align256 = [](size_t x) { return (x + 255) & ~(size_t)255; };

    size_t off = 0;
    const size_t basesOff  = off; off += align256(NB * sizeof(int));
    const size_t totalsOff = off; off += align256(NB * sizeof(int));
    const size_t rn16Off   = off; off += align256((size_t)NMAX * sizeof(__half)); // 2 MB
    const size_t partOff   = off;
    const size_t histBytes = align256((size_t)nTiles * NB * sizeof(int));
    const size_t scanBytes = 2 * histBytes;                    // histG + offG
    const size_t pairsBytes = ((size_t)E + 2 * NB) * sizeof(ull);

    int nSplit = 0;
    size_t partRegion = 0;
    for (int c : {2, 4, 8, 1}) {                   // probe: prefer nSplit=2 (one residency round)
        size_t pr = (size_t)c * NMAX * sizeof(float);
        if (pr < scanBytes) pr = scanBytes;
        if (partOff + pr + pairsBytes <= ws_size) { nSplit = c; partRegion = pr; break; }
    }

    if (nSplit > 0) {
        int*    bases   = (int*)   ((char*)d_ws + basesOff);
        int*    totals  = (int*)   ((char*)d_ws + totalsOff);
        __half* rnorm16 = (__half*)((char*)d_ws + rn16Off);
        float*  partial = (float*) ((char*)d_ws + partOff);
        int*    histG   = (int*)   ((char*)d_ws + partOff);             // alias: dead
        int*    offG    = (int*)   ((char*)d_ws + partOff + histBytes); // before reduce
        ull*    pairs   = (ull*)   ((char*)d_ws + partOff + partRegion);

        hist_kernel            <<<nTiles, BLOCK1, 0, stream>>>(row, histG, E);
        totals_kernel          <<<NB, 256, 0, stream>>>(histG, totals, nTiles);
        bases_kernel           <<<1, NB, 0, stream>>>(totals, bases);
        offsets_kernel         <<<NB, 256, 0, stream>>>(histG, bases, offG, nTiles);
        scatter_kernel         <<<nTiles, BLOCK1, 0, stream>>>(row, edge_attr, offG, pairs, E);
        reduce_kernel          <<<NB * nSplit, BLOCK2, 0, stream>>>(pairs, totals, bases, partial, nSplit);
        recip_kernel           <<<1024, 256, 0, stream>>>(partial, rnorm16, Np, nSplit);
        gather_scale_f16_kernel<<<2048, 256, 0, stream>>>(col, edge_attr, rnorm16, out, E);
    } else {
        float* rowsum = (float*)d_ws;
        const int workE = (E + 3) >> 2;
        int gE = (workE + 255) / 256;
        if (gE > 2048) gE = 2048;
        zero_ws_kernel         <<<2048, 256, 0, stream>>>(rowsum, Np);
        rowsum_atomic_kernel   <<<gE, 256, 0, stream>>>(row, edge_attr, rowsum, E);
        recip_fallback_kernel  <<<2048, 256, 0, stream>>>(rowsum, Np);
        gather_scale_f32_kernel<<<2048, 256, 0, stream>>>(col, edge_attr, rowsum, out, E);
    }
}